// Round 2
// baseline (1239.336 us; speedup 1.0000x reference)
//
#include <hip/hip_runtime.h>

#define N_NODES 20000
#define DIM 256
#define NHEAD 4
#define DHEAD 64
#define NLAYER 2
#define NEDGE 320000
#define KCAP 48
#define NBM 157   // ceil(20000/128)

// =============== dtype sniffer: 1 => inputs are float32, 0 => bf16 ===========
__global__ void sniff_kernel(const unsigned short* __restrict__ p,
                             int* __restrict__ flag) {
    __shared__ int s;
    if (threadIdx.x == 0) s = 0;
    __syncthreads();
    int c = 0;
    for (int i = threadIdx.x; i < 4096; i += 256) {
        unsigned short u = p[i];
        unsigned e = (u >> 7) & 0xFFu;
        if (e == 0xFFu) c++;                 // bf16 inf/nan pattern
        else if (e == 0u && (u & 0x7Fu)) c++; // bf16 denormal pattern
    }
    atomicAdd(&s, c);
    __syncthreads();
    if (threadIdx.x == 0) flag[0] = (s >= 4) ? 1 : 0;
}

// =============== canonical fp32 conversion of all float tensors ==============
struct ConvArgs {
    const void* src[14];
    float*      dst[14];
    int         n[14];
};

__global__ void conv_multi_kernel(ConvArgs a, const int* __restrict__ flag) {
    const int t  = blockIdx.y;
    const int n  = a.n[t];
    const int i0 = (blockIdx.x * 256 + threadIdx.x) * 4;
    if (i0 >= n) return;
    float* dst = a.dst[t];
    if (flag[0]) {
        float4 v = *(const float4*)((const float*)a.src[t] + i0);
        *(float4*)(dst + i0) = v;
    } else {
        ushort4 u = *(const ushort4*)((const unsigned short*)a.src[t] + i0);
        float4 v;
        v.x = __uint_as_float(((unsigned)u.x) << 16);
        v.y = __uint_as_float(((unsigned)u.y) << 16);
        v.z = __uint_as_float(((unsigned)u.z) << 16);
        v.w = __uint_as_float(((unsigned)u.w) << 16);
        *(float4*)(dst + i0) = v;
    }
}

// =============== neighbor build ==============================================
__global__ void zero_cnt_kernel(int* __restrict__ cnt) {
    int i = blockIdx.x * 256 + threadIdx.x;
    if (i < N_NODES) cnt[i] = 0;
}

__global__ void build_nbr_kernel(const int* __restrict__ ei,
                                 int* __restrict__ cnt, int* __restrict__ nbr) {
    int e = blockIdx.x * 256 + threadIdx.x;
    if (e >= NEDGE) return;
    int s = ei[e];           // edge_index[0][e]
    int t = ei[NEDGE + e];   // edge_index[1][e]
    int slot = atomicAdd(&cnt[t], 1);
    if (slot < KCAP) nbr[t * KCAP + slot] = s;
}

// =============== SGEMM: C[M,Nc] = A[M,K] @ B[Nc,K]^T + bias (+gelu) ==========
// 256 threads as 16x16; 8x8 per thread; block tile 128x128; K-step 16.
__global__ __launch_bounds__(256) void sgemm_bt_kernel(
    const float* __restrict__ A, const float* __restrict__ B,
    const float* __restrict__ bias, float* __restrict__ C,
    int M, int Nc, int K, int do_gelu)
{
    __shared__ float As[16][132];   // As[k][m], +4 pad
    __shared__ float Bs[16][132];   // Bs[k][n]
    const int tid = threadIdx.x;
    const int tx  = tid & 15;
    const int ty  = tid >> 4;
    const int m0  = blockIdx.x * 128;
    const int n0  = blockIdx.y * 128;

    float acc[8][8] = {};

    for (int k0 = 0; k0 < K; k0 += 16) {
#pragma unroll
        for (int i = 0; i < 2; ++i) {
            int f   = tid + i * 256;      // 0..511
            int row = f >> 2;
            int kq  = (f & 3) * 4;
            float4 v = make_float4(0.f, 0.f, 0.f, 0.f);
            if (m0 + row < M)
                v = *(const float4*)&A[(size_t)(m0 + row) * K + k0 + kq];
            As[kq + 0][row] = v.x; As[kq + 1][row] = v.y;
            As[kq + 2][row] = v.z; As[kq + 3][row] = v.w;
            float4 w = *(const float4*)&B[(size_t)(n0 + row) * K + k0 + kq];
            Bs[kq + 0][row] = w.x; Bs[kq + 1][row] = w.y;
            Bs[kq + 2][row] = w.z; Bs[kq + 3][row] = w.w;
        }
        __syncthreads();
#pragma unroll
        for (int kk = 0; kk < 16; ++kk) {
            float a[8], b[8];
#pragma unroll
            for (int i = 0; i < 8; ++i) a[i] = As[kk][ty * 8 + i];
#pragma unroll
            for (int j = 0; j < 8; ++j) b[j] = Bs[kk][tx * 8 + j];
#pragma unroll
            for (int i = 0; i < 8; ++i)
#pragma unroll
                for (int j = 0; j < 8; ++j)
                    acc[i][j] = fmaf(a[i], b[j], acc[i][j]);
        }
        __syncthreads();
    }

    const int col0 = n0 + tx * 8;
    float bv[8];
#pragma unroll
    for (int j = 0; j < 8; ++j) bv[j] = bias[col0 + j];

#pragma unroll
    for (int i = 0; i < 8; ++i) {
        int row = m0 + ty * 8 + i;
        if (row >= M) continue;
        float o[8];
#pragma unroll
        for (int j = 0; j < 8; ++j) {
            float v = acc[i][j] + bv[j];
            if (do_gelu) v = 0.5f * v * (1.0f + erff(v * 0.7071067811865475f));
            o[j] = v;
        }
        *(float4*)&C[(size_t)row * Nc + col0]     = make_float4(o[0], o[1], o[2], o[3]);
        *(float4*)&C[(size_t)row * Nc + col0 + 4] = make_float4(o[4], o[5], o[6], o[7]);
    }
}

// =============== attention: block per node, wave per head ====================
__global__ __launch_bounds__(256) void attn_kernel(
    const float* __restrict__ q,    // [N, 256]
    const float* __restrict__ kv,   // [N, 512]  (k | v)
    const int* __restrict__ nbr,    // [N, KCAP]
    const int* __restrict__ cnt,    // [N]
    float* __restrict__ ao)         // [N, 256]
{
    const int n    = blockIdx.x;
    const int tid  = threadIdx.x;
    const int h    = tid >> 6;
    const int lane = tid & 63;

    __shared__ float sc[NHEAD][KCAP];
    __shared__ int   nbs[KCAP];

    int deg = cnt[n];
    if (deg > KCAP) deg = KCAP;
    const bool iso = (deg == 0);
    if (iso) deg = 1;

    if (tid < KCAP) {
        int j  = tid;
        int nb = (j < deg) ? (iso ? n : nbr[n * KCAP + j]) : 0;
        nbs[j] = nb;
    }
    __syncthreads();

    const float qv = q[(size_t)n * DIM + h * DHEAD + lane];

    for (int j = 0; j < deg; ++j) {
        int nb   = nbs[j];
        float kx = kv[(size_t)nb * 512 + h * DHEAD + lane];
        float p  = qv * kx;
#pragma unroll
        for (int m = 32; m >= 1; m >>= 1) p += __shfl_xor(p, m, 64);
        if (lane == 0) sc[h][j] = p * 0.125f;   // 1/sqrt(64)
    }
    __syncthreads();

    float s  = (lane < deg) ? sc[h][lane] : -1e30f;
    float mx = s;
#pragma unroll
    for (int m = 32; m >= 1; m >>= 1) mx = fmaxf(mx, __shfl_xor(mx, m, 64));
    float e   = (lane < deg) ? __expf(s - mx) : 0.0f;
    float sum = e;
#pragma unroll
    for (int m = 32; m >= 1; m >>= 1) sum += __shfl_xor(sum, m, 64);
    float inv = 1.0f / sum;
    if (lane < KCAP) sc[h][lane] = e * inv;
    __syncthreads();

    float accv = 0.0f;
    for (int j = 0; j < deg; ++j) {
        int nb   = nbs[j];
        float vx = kv[(size_t)nb * 512 + 256 + h * DHEAD + lane];
        accv = fmaf(sc[h][j], vx, accv);
    }
    ao[(size_t)n * DIM + h * DHEAD + lane] = accv;
}

// =============== fused residual-add + layernorm, wave per row ================
__global__ __launch_bounds__(256) void ln_add_kernel(
    const float* __restrict__ xin, const float* __restrict__ t,
    const float* __restrict__ g, const float* __restrict__ b,
    float* __restrict__ xout)
{
    const int wave = threadIdx.x >> 6;
    const int lane = threadIdx.x & 63;
    const int row  = blockIdx.x * 4 + wave;

    float4 xv = *(const float4*)&xin[(size_t)row * DIM + lane * 4];
    float4 tv = *(const float4*)&t[(size_t)row * DIM + lane * 4];
    float v[4] = { xv.x + tv.x, xv.y + tv.y, xv.z + tv.z, xv.w + tv.w };
    float s = 0.f, ss = 0.f;
#pragma unroll
    for (int i = 0; i < 4; ++i) { s += v[i]; ss += v[i] * v[i]; }
#pragma unroll
    for (int m = 32; m >= 1; m >>= 1) {
        s  += __shfl_xor(s, m, 64);
        ss += __shfl_xor(ss, m, 64);
    }
    const float mu  = s * (1.0f / DIM);
    const float var = ss * (1.0f / DIM) - mu * mu;
    const float r   = rsqrtf(var + 1e-5f);
    float o[4];
#pragma unroll
    for (int i = 0; i < 4; ++i) {
        int c = lane * 4 + i;
        o[i] = (v[i] - mu) * r * g[c] + b[c];
    }
    *(float4*)&xout[(size_t)row * DIM + lane * 4] = make_float4(o[0], o[1], o[2], o[3]);
}

// =============== emit: fp32 x -> d_out in the detected dtype =================
__global__ void emit_kernel(const float* __restrict__ x, void* __restrict__ out,
                            const int* __restrict__ flag) {
    int i0 = (blockIdx.x * 256 + threadIdx.x) * 4;
    if (i0 >= N_NODES * DIM) return;
    float4 v = *(const float4*)(x + i0);
    if (flag[0]) {
        *(float4*)((float*)out + i0) = v;
    } else {
        __bf16 b0 = (__bf16)v.x, b1 = (__bf16)v.y, b2 = (__bf16)v.z, b3 = (__bf16)v.w;
        ushort4 u;
        u.x = *(unsigned short*)&b0; u.y = *(unsigned short*)&b1;
        u.z = *(unsigned short*)&b2; u.w = *(unsigned short*)&b3;
        *(ushort4*)((unsigned short*)out + i0) = u;
    }
}

// =============== launch ======================================================
extern "C" void kernel_launch(void* const* d_in, const int* in_sizes, int n_in,
                              void* d_out, int out_size, void* d_ws, size_t ws_size,
                              hipStream_t stream) {
    const int* ei = (const int*)d_in[14];

    char* ws = (char*)d_ws;
    size_t off = 0;
    auto alloc = [&](size_t bytes) -> void* {
        void* p = ws + off;
        off = (off + bytes + 255) & ~(size_t)255;
        return p;
    };

    // element counts per d_in slot (float tensors 0..13)
    const int nelem[14] = {
        N_NODES * DIM,            // expr_embed
        N_NODES * DIM,            // spatial_embed
        NLAYER * 3 * DIM * DIM,   // in_proj_w
        NLAYER * 3 * DIM,         // in_proj_b
        NLAYER * DIM * DIM,       // out_proj_w
        NLAYER * DIM,             // out_proj_b
        NLAYER * 2 * DIM * DIM,   // ffn_w1
        NLAYER * 2 * DIM,         // ffn_b1
        NLAYER * DIM * 2 * DIM,   // ffn_w2
        NLAYER * DIM,             // ffn_b2
        NLAYER * DIM,             // ln1_g
        NLAYER * DIM,             // ln1_b
        NLAYER * DIM,             // ln2_g
        NLAYER * DIM              // ln2_b
    };

    ConvArgs ca;
    float* canon[14];
    for (int i = 0; i < 14; ++i) {
        canon[i] = (float*)alloc((size_t)nelem[i] * 4);
        ca.src[i] = d_in[i];
        ca.dst[i] = canon[i];
        ca.n[i]   = nelem[i];
    }

    float* x_buf  = (float*)alloc((size_t)N_NODES * DIM * 4);
    float* q_buf  = (float*)alloc((size_t)N_NODES * DIM * 4);       // aliases t
    float* kv_buf = (float*)alloc((size_t)N_NODES * 2 * DIM * 4);
    float* h_buf  = (float*)alloc((size_t)N_NODES * 2 * DIM * 4);   // ao = first half
    float* ao_buf = h_buf;
    float* t_buf  = q_buf;
    int* cnt  = (int*)alloc((size_t)N_NODES * 4);
    int* nbr  = (int*)alloc((size_t)N_NODES * KCAP * 4);
    int* flag = (int*)alloc(256);

    sniff_kernel<<<1, 256, 0, stream>>>((const unsigned short*)d_in[0], flag);
    {
        int maxb = (nelem[0] + 1023) / 1024;   // largest tensor, 4 elems/thread
        conv_multi_kernel<<<dim3(maxb, 14), 256, 0, stream>>>(ca, flag);
    }
    zero_cnt_kernel<<<(N_NODES + 255) / 256, 256, 0, stream>>>(cnt);
    build_nbr_kernel<<<(NEDGE + 255) / 256, 256, 0, stream>>>(ei, cnt, nbr);

    const float* expr = canon[0];
    const float* spat = canon[1];

    for (int i = 0; i < NLAYER; ++i) {
        const float* Wqkv = canon[2] + (size_t)i * 3 * DIM * DIM;
        const float* bqkv = canon[3] + (size_t)i * 3 * DIM;
        const float* xin  = (i == 0) ? expr : x_buf;

        // q = x @ Wq^T + bq
        sgemm_bt_kernel<<<dim3(NBM, 2), 256, 0, stream>>>(
            xin, Wqkv, bqkv, q_buf, N_NODES, DIM, DIM, 0);
        // kv = spatial @ [Wk;Wv]^T + [bk;bv]
        sgemm_bt_kernel<<<dim3(NBM, 4), 256, 0, stream>>>(
            spat, Wqkv + (size_t)DIM * DIM, bqkv + DIM, kv_buf, N_NODES, 2 * DIM, DIM, 0);
        // attention
        attn_kernel<<<N_NODES, 256, 0, stream>>>(q_buf, kv_buf, nbr, cnt, ao_buf);
        // t = ao @ Wo^T + bo   (t aliases q: q fully consumed by attn)
        sgemm_bt_kernel<<<dim3(NBM, 2), 256, 0, stream>>>(
            ao_buf, canon[4] + (size_t)i * DIM * DIM, canon[5] + (size_t)i * DIM,
            t_buf, N_NODES, DIM, DIM, 0);
        // x = LN(xin + t)
        ln_add_kernel<<<N_NODES / 4, 256, 0, stream>>>(
            xin, t_buf, canon[10] + (size_t)i * DIM, canon[11] + (size_t)i * DIM, x_buf);
        // h = gelu(x @ W1^T + b1)   (h overwrites ao region: ao fully consumed)
        sgemm_bt_kernel<<<dim3(NBM, 4), 256, 0, stream>>>(
            x_buf, canon[6] + (size_t)i * 2 * DIM * DIM, canon[7] + (size_t)i * 2 * DIM,
            h_buf, N_NODES, 2 * DIM, DIM, 1);
        // t = h @ W2^T + b2
        sgemm_bt_kernel<<<dim3(NBM, 2), 256, 0, stream>>>(
            h_buf, canon[8] + (size_t)i * DIM * 2 * DIM, canon[9] + (size_t)i * DIM,
            t_buf, N_NODES, DIM, 2 * DIM, 0);
        // x = LN(x + t)
        ln_add_kernel<<<N_NODES / 4, 256, 0, stream>>>(
            x_buf, t_buf, canon[12] + (size_t)i * DIM, canon[13] + (size_t)i * DIM, x_buf);
    }

    emit_kernel<<<(N_NODES * DIM) / 1024, 256, 0, stream>>>(x_buf, d_out, flag);
}

// Round 4
// 647.218 us; speedup vs baseline: 1.9149x; 1.9149x over previous
//
#include <hip/hip_runtime.h>

#define N_NODES 20000
#define DIM 256
#define NHEAD 4
#define DHEAD 64
#define NLAYER 2
#define NEDGE 320000
#define KCAP 48
#define NBM 157   // ceil(20000/128)

typedef __bf16 v8bf __attribute__((ext_vector_type(8)));
typedef float v4f __attribute__((ext_vector_type(4)));

union BfPack { unsigned short us[8]; v8bf v; };

__device__ __forceinline__ unsigned short f2bf(float f) {
    unsigned u = __float_as_uint(f);
    unsigned r = u + 0x7FFFu + ((u >> 16) & 1u);   // round-to-nearest-even
    return (unsigned short)(r >> 16);
}

// =============== dtype sniffer: 1 => inputs are float32, 0 => bf16 ===========
__global__ void sniff_kernel(const unsigned short* __restrict__ p,
                             int* __restrict__ flag) {
    __shared__ int s;
    if (threadIdx.x == 0) s = 0;
    __syncthreads();
    int c = 0;
    for (int i = threadIdx.x; i < 4096; i += 256) {
        unsigned short u = p[i];
        unsigned e = (u >> 7) & 0xFFu;
        if (e == 0xFFu) c++;                  // bf16 inf/nan pattern
        else if (e == 0u && (u & 0x7Fu)) c++; // bf16 denormal pattern
    }
    atomicAdd(&s, c);
    __syncthreads();
    if (threadIdx.x == 0) flag[0] = (s >= 4) ? 1 : 0;
}

// =============== canonical fp32 conversion of all float tensors ==============
struct ConvArgs {
    const void* src[14];
    float*      dst[14];
    int         n[14];
};

__global__ void conv_multi_kernel(ConvArgs a, const int* __restrict__ flag) {
    const int t  = blockIdx.y;
    const int n  = a.n[t];
    const int i0 = (blockIdx.x * 256 + threadIdx.x) * 4;
    if (i0 >= n) return;
    float* dst = a.dst[t];
    if (flag[0]) {
        float4 v = *(const float4*)((const float*)a.src[t] + i0);
        *(float4*)(dst + i0) = v;
    } else {
        ushort4 u = *(const ushort4*)((const unsigned short*)a.src[t] + i0);
        float4 v;
        v.x = __uint_as_float(((unsigned)u.x) << 16);
        v.y = __uint_as_float(((unsigned)u.y) << 16);
        v.z = __uint_as_float(((unsigned)u.z) << 16);
        v.w = __uint_as_float(((unsigned)u.w) << 16);
        *(float4*)(dst + i0) = v;
    }
}

// =============== neighbor build ==============================================
__global__ void zero_cnt_kernel(int* __restrict__ cnt) {
    int i = blockIdx.x * 256 + threadIdx.x;
    if (i < N_NODES) cnt[i] = 0;
}

__global__ void build_nbr_kernel(const int* __restrict__ ei,
                                 int* __restrict__ cnt, int* __restrict__ nbr) {
    int e = blockIdx.x * 256 + threadIdx.x;
    if (e >= NEDGE) return;
    int s = ei[e];           // edge_index[0][e]
    int t = ei[NEDGE + e];   // edge_index[1][e]
    int slot = atomicAdd(&cnt[t], 1);
    if (slot < KCAP) nbr[t * KCAP + slot] = s;
}

// === MFMA GEMM: C[M,Nc] = A[M,K] @ B[Nc,K]^T + bias (+gelu), fp32 in/out =====
// fp32 canon inputs, bf16 RNE in staging, fp32 MFMA accumulate, fp32 store.
__global__ __launch_bounds__(256) void gemm_f32mfma_kernel(
    const float* __restrict__ A, const float* __restrict__ B,
    const float* __restrict__ bias, float* __restrict__ C,
    int M, int Nc, int Kd, int do_gelu)
{
    __shared__ __align__(16) __bf16 As[128][72];  // +8 pad
    __shared__ __align__(16) __bf16 Bs[128][72];
    const int tid  = threadIdx.x;
    const int m0   = blockIdx.x * 128;
    const int n0   = blockIdx.y * 128;
    const int wave = tid >> 6;
    const int lane = tid & 63;
    const int wm   = (wave >> 1) * 64;
    const int wn   = (wave & 1) * 64;
    const int lm   = lane & 15;
    const int lk   = (lane >> 4) * 8;

    v4f acc[4][4] = {};

    for (int k0 = 0; k0 < Kd; k0 += 64) {
#pragma unroll
        for (int i = 0; i < 4; ++i) {
            int c   = i * 256 + tid;
            int row = c >> 3;
            int col = (c & 7) << 3;
            float4 a0 = make_float4(0.f, 0.f, 0.f, 0.f), a1 = a0;
            if (m0 + row < M) {
                a0 = *(const float4*)&A[(size_t)(m0 + row) * Kd + k0 + col];
                a1 = *(const float4*)&A[(size_t)(m0 + row) * Kd + k0 + col + 4];
            }
            BfPack pa;
            pa.us[0] = f2bf(a0.x); pa.us[1] = f2bf(a0.y);
            pa.us[2] = f2bf(a0.z); pa.us[3] = f2bf(a0.w);
            pa.us[4] = f2bf(a1.x); pa.us[5] = f2bf(a1.y);
            pa.us[6] = f2bf(a1.z); pa.us[7] = f2bf(a1.w);
            *(v8bf*)&As[row][col] = pa.v;
            float4 b0 = *(const float4*)&B[(size_t)(n0 + row) * Kd + k0 + col];
            float4 b1 = *(const float4*)&B[(size_t)(n0 + row) * Kd + k0 + col + 4];
            BfPack pb;
            pb.us[0] = f2bf(b0.x); pb.us[1] = f2bf(b0.y);
            pb.us[2] = f2bf(b0.z); pb.us[3] = f2bf(b0.w);
            pb.us[4] = f2bf(b1.x); pb.us[5] = f2bf(b1.y);
            pb.us[6] = f2bf(b1.z); pb.us[7] = f2bf(b1.w);
            *(v8bf*)&Bs[row][col] = pb.v;
        }
        __syncthreads();
#pragma unroll
        for (int ks = 0; ks < 2; ++ks) {
            v8bf af[4], bq[4];
#pragma unroll
            for (int mi = 0; mi < 4; ++mi)
                af[mi] = *(const v8bf*)&As[wm + mi * 16 + lm][ks * 32 + lk];
#pragma unroll
            for (int ni = 0; ni < 4; ++ni)
                bq[ni] = *(const v8bf*)&Bs[wn + ni * 16 + lm][ks * 32 + lk];
#pragma unroll
            for (int mi = 0; mi < 4; ++mi)
#pragma unroll
                for (int ni = 0; ni < 4; ++ni)
                    acc[mi][ni] = __builtin_amdgcn_mfma_f32_16x16x32_bf16(
                        af[mi], bq[ni], acc[mi][ni], 0, 0, 0);
        }
        __syncthreads();
    }

    // D layout: col = lane&15, row = (lane>>4)*4 + r  (m89-verified)
    const int rq = (lane >> 4) << 2;
#pragma unroll
    for (int ni = 0; ni < 4; ++ni) {
        int col  = n0 + wn + ni * 16 + lm;
        float bv = bias[col];
#pragma unroll
        for (int mi = 0; mi < 4; ++mi) {
#pragma unroll
            for (int r = 0; r < 4; ++r) {
                int row = m0 + wm + mi * 16 + rq + r;
                if (row >= M) continue;
                float v = acc[mi][ni][r] + bv;
                if (do_gelu) v = 0.5f * v * (1.0f + erff(v * 0.7071067811865475f));
                C[(size_t)row * Nc + col] = v;
            }
        }
    }
}

// =============== attention: block per node, wave per head (fp32) =============
// Score phase: 8 lane-groups of 8 handle 8 neighbors in parallel;
// each group: 8 FMAs + 3 intra-group shuffles per 64-dot.
__global__ __launch_bounds__(256) void attn_kernel(
    const float* __restrict__ q,    // [N, 256]
    const float* __restrict__ kv,   // [N, 512]  (k | v)
    const int* __restrict__ nbr,    // [N, KCAP]
    const int* __restrict__ cnt,    // [N]
    float* __restrict__ ao)         // [N, 256]
{
    const int n    = blockIdx.x;
    const int tid  = threadIdx.x;
    const int h    = tid >> 6;
    const int lane = tid & 63;
    const int sub  = lane & 7;
    const int grp  = lane >> 3;

    __shared__ float sc[NHEAD][KCAP];
    __shared__ int   nbs[KCAP];

    int deg = cnt[n];
    if (deg > KCAP) deg = KCAP;
    const bool iso = (deg == 0);
    if (iso) deg = 1;

    if (tid < KCAP)
        nbs[tid] = (tid < deg) ? (iso ? n : nbr[n * KCAP + tid]) : 0;
    __syncthreads();

    float qf[8];
    {
        float4 q0 = *(const float4*)&q[(size_t)n * DIM + h * DHEAD + sub * 8];
        float4 q1 = *(const float4*)&q[(size_t)n * DIM + h * DHEAD + sub * 8 + 4];
        qf[0] = q0.x; qf[1] = q0.y; qf[2] = q0.z; qf[3] = q0.w;
        qf[4] = q1.x; qf[5] = q1.y; qf[6] = q1.z; qf[7] = q1.w;
    }

    const int nit = (deg + 7) >> 3;
    for (int it = 0; it < nit; ++it) {
        int j  = it * 8 + grp;
        int jc = (j < deg) ? j : (deg - 1);
        int nb = nbs[jc];
        float4 k0 = *(const float4*)&kv[(size_t)nb * 512 + h * DHEAD + sub * 8];
        float4 k1 = *(const float4*)&kv[(size_t)nb * 512 + h * DHEAD + sub * 8 + 4];
        float p = qf[0] * k0.x;
        p = fmaf(qf[1], k0.y, p); p = fmaf(qf[2], k0.z, p); p = fmaf(qf[3], k0.w, p);
        p = fmaf(qf[4], k1.x, p); p = fmaf(qf[5], k1.y, p);
        p = fmaf(qf[6], k1.z, p); p = fmaf(qf[7], k1.w, p);
        p += __shfl_xor(p, 1, 64);
        p += __shfl_xor(p, 2, 64);
        p += __shfl_xor(p, 4, 64);
        if (sub == 0 && j < deg) sc[h][j] = p * 0.125f;   // 1/sqrt(64)
    }
    __syncthreads();

    float s  = (lane < deg) ? sc[h][lane] : -1e30f;
    float mx = s;
#pragma unroll
    for (int m = 32; m >= 1; m >>= 1) mx = fmaxf(mx, __shfl_xor(mx, m, 64));
    float e   = (lane < deg) ? __expf(s - mx) : 0.0f;
    float sum = e;
#pragma unroll
    for (int m = 32; m >= 1; m >>= 1) sum += __shfl_xor(sum, m, 64);
    float inv = 1.0f / sum;
    if (lane < KCAP) sc[h][lane] = e * inv;
    __syncthreads();

    float accv = 0.0f;
    for (int j = 0; j < deg; ++j) {
        int nb   = nbs[j];
        float vx = kv[(size_t)nb * 512 + 256 + h * DHEAD + lane];
        accv = fmaf(sc[h][j], vx, accv);
    }
    ao[(size_t)n * DIM + h * DHEAD + lane] = accv;
}

// =============== fused residual-add + layernorm, wave per row ================
__global__ __launch_bounds__(256) void ln_add_kernel(
    const float* __restrict__ xin, const float* __restrict__ t,
    const float* __restrict__ g, const float* __restrict__ b,
    float* __restrict__ xout)
{
    const int wave = threadIdx.x >> 6;
    const int lane = threadIdx.x & 63;
    const int row  = blockIdx.x * 4 + wave;

    float4 xv = *(const float4*)&xin[(size_t)row * DIM + lane * 4];
    float4 tv = *(const float4*)&t[(size_t)row * DIM + lane * 4];
    float v[4] = { xv.x + tv.x, xv.y + tv.y, xv.z + tv.z, xv.w + tv.w };
    float s = 0.f, ss = 0.f;
#pragma unroll
    for (int i = 0; i < 4; ++i) { s += v[i]; ss += v[i] * v[i]; }
#pragma unroll
    for (int m = 32; m >= 1; m >>= 1) {
        s  += __shfl_xor(s, m, 64);
        ss += __shfl_xor(ss, m, 64);
    }
    const float mu  = s * (1.0f / DIM);
    const float var = ss * (1.0f / DIM) - mu * mu;
    const float r   = rsqrtf(var + 1e-5f);
    float o[4];
#pragma unroll
    for (int i = 0; i < 4; ++i) {
        int c = lane * 4 + i;
        o[i] = (v[i] - mu) * r * g[c] + b[c];
    }
    *(float4*)&xout[(size_t)row * DIM + lane * 4] = make_float4(o[0], o[1], o[2], o[3]);
}

// =============== emit: fp32 x -> d_out in the detected dtype =================
__global__ void emit_kernel(const float* __restrict__ x, void* __restrict__ out,
                            const int* __restrict__ flag) {
    int i0 = (blockIdx.x * 256 + threadIdx.x) * 4;
    if (i0 >= N_NODES * DIM) return;
    float4 v = *(const float4*)(x + i0);
    if (flag[0]) {
        *(float4*)((float*)out + i0) = v;
    } else {
        ushort4 u;
        u.x = f2bf(v.x); u.y = f2bf(v.y); u.z = f2bf(v.z); u.w = f2bf(v.w);
        *(ushort4*)((unsigned short*)out + i0) = u;
    }
}

// =============== launch ======================================================
extern "C" void kernel_launch(void* const* d_in, const int* in_sizes, int n_in,
                              void* d_out, int out_size, void* d_ws, size_t ws_size,
                              hipStream_t stream) {
    const int* ei = (const int*)d_in[14];

    char* ws = (char*)d_ws;
    size_t off = 0;
    auto alloc = [&](size_t bytes) -> void* {
        void* p = ws + off;
        off = (off + bytes + 255) & ~(size_t)255;
        return p;
    };

    const int nelem[14] = {
        N_NODES * DIM, N_NODES * DIM,
        NLAYER * 3 * DIM * DIM, NLAYER * 3 * DIM,
        NLAYER * DIM * DIM,     NLAYER * DIM,
        NLAYER * 2 * DIM * DIM, NLAYER * 2 * DIM,
        NLAYER * DIM * 2 * DIM, NLAYER * DIM,
        NLAYER * DIM, NLAYER * DIM, NLAYER * DIM, NLAYER * DIM
    };

    ConvArgs ca;
    float* canon[14];
    for (int i = 0; i < 14; ++i) {
        canon[i] = (float*)alloc((size_t)nelem[i] * 4);
        ca.src[i] = d_in[i];
        ca.dst[i] = canon[i];
        ca.n[i]   = nelem[i];
    }

    float* x_buf  = (float*)alloc((size_t)N_NODES * DIM * 4);
    float* q_buf  = (float*)alloc((size_t)N_NODES * DIM * 4);       // aliases t
    float* kv_buf = (float*)alloc((size_t)N_NODES * 2 * DIM * 4);
    float* h_buf  = (float*)alloc((size_t)N_NODES * 2 * DIM * 4);   // ao = first half
    float* ao_buf = h_buf;
    float* t_buf  = q_buf;
    int* cnt  = (int*)alloc((size_t)N_NODES * 4);
    int* nbr  = (int*)alloc((size_t)N_NODES * KCAP * 4);
    int* flag = (int*)alloc(256);

    sniff_kernel<<<1, 256, 0, stream>>>((const unsigned short*)d_in[0], flag);
    {
        int maxb = (nelem[0] + 1023) / 1024;
        conv_multi_kernel<<<dim3(maxb, 14), 256, 0, stream>>>(ca, flag);
    }
    zero_cnt_kernel<<<(N_NODES + 255) / 256, 256, 0, stream>>>(cnt);
    build_nbr_kernel<<<(NEDGE + 255) / 256, 256, 0, stream>>>(ei, cnt, nbr);

    const float* expr = canon[0];
    const float* spat = canon[1];

    for (int i = 0; i < NLAYER; ++i) {
        const float* Wqkv = canon[2] + (size_t)i * 3 * DIM * DIM;
        const float* bqkv = canon[3] + (size_t)i * 3 * DIM;
        const float* xin  = (i == 0) ? expr : x_buf;

        gemm_f32mfma_kernel<<<dim3(NBM, 2), 256, 0, stream>>>(
            xin, Wqkv, bqkv, q_buf, N_NODES, DIM, DIM, 0);
        gemm_f32mfma_kernel<<<dim3(NBM, 4), 256, 0, stream>>>(
            spat, Wqkv + (size_t)DIM * DIM, bqkv + DIM, kv_buf, N_NODES, 2 * DIM, DIM, 0);
        attn_kernel<<<N_NODES, 256, 0, stream>>>(q_buf, kv_buf, nbr, cnt, ao_buf);
        gemm_f32mfma_kernel<<<dim3(NBM, 2), 256, 0, stream>>>(
            ao_buf, canon[4] + (size_t)i * DIM * DIM, canon[5] + (size_t)i * DIM,
            t_buf, N_NODES, DIM, DIM, 0);
        ln_add_kernel<<<N_NODES / 4, 256, 0, stream>>>(
            xin, t_buf, canon[10] + (size_t)i * DIM, canon[11] + (size_t)i * DIM, x_buf);
        gemm_f32mfma_kernel<<<dim3(NBM, 4), 256, 0, stream>>>(
            x_buf, canon[6] + (size_t)i * 2 * DIM * DIM, canon[7] + (size_t)i * 2 * DIM,
            h_buf, N_NODES, 2 * DIM, DIM, 1);
        gemm_f32mfma_kernel<<<dim3(NBM, 2), 256, 0, stream>>>(
            h_buf, canon[8] + (size_t)i * DIM * 2 * DIM, canon[9] + (size_t)i * DIM,
            t_buf, N_NODES, DIM, 2 * DIM, 0);
        ln_add_kernel<<<N_NODES / 4, 256, 0, stream>>>(
            x_buf, t_buf, canon[12] + (size_t)i * DIM, canon[13] + (size_t)i * DIM, x_buf);
    }

    emit_kernel<<<(N_NODES * DIM) / 1024, 256, 0, stream>>>(x_buf, d_out, flag);
}

// Round 7
// 614.351 us; speedup vs baseline: 2.0173x; 1.0535x over previous
//
#include <hip/hip_runtime.h>

#define N_NODES 20000
#define DIM 256
#define NHEAD 4
#define DHEAD 64
#define NLAYER 2
#define NEDGE 320000
#define KCAP 48
#define NBM 157   // ceil(20000/128)

typedef __bf16 v8bf __attribute__((ext_vector_type(8)));
typedef float v4f __attribute__((ext_vector_type(4)));

union LU     { uint4 u; v8bf v; };
union BfPack { unsigned short us[8]; v8bf v; };

__device__ __forceinline__ unsigned short f2bf(float f) {
    unsigned u = __float_as_uint(f);
    unsigned r = u + 0x7FFFu + ((u >> 16) & 1u);   // RNE
    return (unsigned short)(r >> 16);
}
__device__ __forceinline__ float bflo(unsigned u) { return __uint_as_float(u << 16); }
__device__ __forceinline__ float bfhi(unsigned u) { return __uint_as_float(u & 0xFFFF0000u); }

// =============== dtype sniffer: 1 => inputs are float32, 0 => bf16 ===========
__global__ void sniff_kernel(const unsigned short* __restrict__ p,
                             int* __restrict__ flag) {
    __shared__ int s;
    if (threadIdx.x == 0) s = 0;
    __syncthreads();
    int c = 0;
    for (int i = threadIdx.x; i < 4096; i += 256) {
        unsigned short u = p[i];
        unsigned e = (u >> 7) & 0xFFu;
        if (e == 0xFFu) c++;                  // bf16 inf/nan pattern
        else if (e == 0u && (u & 0x7Fu)) c++; // bf16 denormal pattern
    }
    atomicAdd(&s, c);
    __syncthreads();
    if (threadIdx.x == 0) flag[0] = (s >= 4) ? 1 : 0;
}

// ===== conv to fp32 canon (embeds/biases/LN params): 9 tensors ===============
struct ConvF32Args { const void* src[9]; float* dst[9]; int n[9]; };

__global__ void conv_f32_kernel(ConvF32Args a, const int* __restrict__ flag) {
    const int t  = blockIdx.y;
    const int n  = a.n[t];
    const int i0 = (blockIdx.x * 256 + threadIdx.x) * 4;
    if (i0 >= n) return;
    float* dst = a.dst[t];
    if (flag[0]) {
        float4 v = *(const float4*)((const float*)a.src[t] + i0);
        *(float4*)(dst + i0) = v;
    } else {
        ushort4 u = *(const ushort4*)((const unsigned short*)a.src[t] + i0);
        *(float4*)(dst + i0) = make_float4(bflo(u.x), bflo(u.y), bflo(u.z), bflo(u.w));
    }
}

// ===== conv to bf16 canon (spatial embed + weights): 5 tensors ===============
struct ConvBfArgs { const void* src[5]; unsigned short* dst[5]; int n[5]; };

__global__ void conv_bf16_kernel(ConvBfArgs a, const int* __restrict__ flag) {
    const int t  = blockIdx.y;
    const int n  = a.n[t];
    const int i0 = (blockIdx.x * 256 + threadIdx.x) * 4;
    if (i0 >= n) return;
    unsigned short* dst = a.dst[t];
    if (flag[0]) {
        float4 v = *(const float4*)((const float*)a.src[t] + i0);
        ushort4 o;
        o.x = f2bf(v.x); o.y = f2bf(v.y); o.z = f2bf(v.z); o.w = f2bf(v.w);
        *(ushort4*)(dst + i0) = o;
    } else {
        ushort4 u = *(const ushort4*)((const unsigned short*)a.src[t] + i0);
        *(ushort4*)(dst + i0) = u;
    }
}

// =============== neighbor build ==============================================
__global__ void zero_cnt_kernel(int* __restrict__ cnt) {
    int i = blockIdx.x * 256 + threadIdx.x;
    if (i < N_NODES) cnt[i] = 0;
}

__global__ void build_nbr_kernel(const int* __restrict__ ei,
                                 int* __restrict__ cnt, int* __restrict__ nbr) {
    int e = blockIdx.x * 256 + threadIdx.x;
    if (e >= NEDGE) return;
    int s = ei[e];
    int t = ei[NEDGE + e];
    int slot = atomicAdd(&cnt[t], 1);
    if (slot < KCAP) nbr[t * KCAP + slot] = s;
}

// ==== MFMA GEMM: C[M,Nc] = A[M,K] @ B[Nc,K]^T + bias (+gelu) =================
// B always bf16 canon. A: fp32 (a_bf=0, f2bf staged) or bf16 (a_bf=1).
// C: fp32 (c_bf=0) or bf16 (c_bf=1). M-guarded (r3-proven skeleton).
__global__ __launch_bounds__(256) void gemm_kernel(
    const void* __restrict__ A, const unsigned short* __restrict__ B,
    const float* __restrict__ bias, void* __restrict__ C,
    int M, int Nc, int Kd, int a_bf, int c_bf, int do_gelu)
{
    __shared__ __align__(16) __bf16 As[128][72];  // +8 pad
    __shared__ __align__(16) __bf16 Bs[128][72];
    const int tid  = threadIdx.x;
    const int m0   = blockIdx.x * 128;
    const int n0   = blockIdx.y * 128;
    const int wave = tid >> 6;
    const int lane = tid & 63;
    const int wm   = (wave >> 1) * 64;
    const int wn   = (wave & 1) * 64;
    const int lm   = lane & 15;
    const int lk   = (lane >> 4) * 8;

    v4f acc[4][4] = {};

    for (int k0 = 0; k0 < Kd; k0 += 64) {
#pragma unroll
        for (int i = 0; i < 4; ++i) {
            int c   = i * 256 + tid;
            int row = c >> 3;
            int col = (c & 7) << 3;
            if (a_bf) {
                uint4 u = make_uint4(0u, 0u, 0u, 0u);
                if (m0 + row < M)
                    u = *(const uint4*)&((const unsigned short*)A)[(size_t)(m0 + row) * Kd + k0 + col];
                LU ta; ta.u = u;
                *(v8bf*)&As[row][col] = ta.v;
            } else {
                float4 a0 = make_float4(0.f, 0.f, 0.f, 0.f), a1 = a0;
                if (m0 + row < M) {
                    a0 = *(const float4*)&((const float*)A)[(size_t)(m0 + row) * Kd + k0 + col];
                    a1 = *(const float4*)&((const float*)A)[(size_t)(m0 + row) * Kd + k0 + col + 4];
                }
                BfPack pa;
                pa.us[0] = f2bf(a0.x); pa.us[1] = f2bf(a0.y);
                pa.us[2] = f2bf(a0.z); pa.us[3] = f2bf(a0.w);
                pa.us[4] = f2bf(a1.x); pa.us[5] = f2bf(a1.y);
                pa.us[6] = f2bf(a1.z); pa.us[7] = f2bf(a1.w);
                *(v8bf*)&As[row][col] = pa.v;
            }
            LU tb;
            tb.u = *(const uint4*)&B[(size_t)(n0 + row) * Kd + k0 + col];
            *(v8bf*)&Bs[row][col] = tb.v;
        }
        __syncthreads();
#pragma unroll
        for (int ks = 0; ks < 2; ++ks) {
            v8bf af[4], bq[4];
#pragma unroll
            for (int mi = 0; mi < 4; ++mi)
                af[mi] = *(const v8bf*)&As[wm + mi * 16 + lm][ks * 32 + lk];
#pragma unroll
            for (int ni = 0; ni < 4; ++ni)
                bq[ni] = *(const v8bf*)&Bs[wn + ni * 16 + lm][ks * 32 + lk];
#pragma unroll
            for (int mi = 0; mi < 4; ++mi)
#pragma unroll
                for (int ni = 0; ni < 4; ++ni)
                    acc[mi][ni] = __builtin_amdgcn_mfma_f32_16x16x32_bf16(
                        af[mi], bq[ni], acc[mi][ni], 0, 0, 0);
        }
        __syncthreads();
    }

    // D layout: col = lane&15, row = (lane>>4)*4 + r  (m89-verified)
    const int rq = (lane >> 4) << 2;
#pragma unroll
    for (int ni = 0; ni < 4; ++ni) {
        int col  = n0 + wn + ni * 16 + lm;
        float bv = bias[col];
#pragma unroll
        for (int mi = 0; mi < 4; ++mi) {
#pragma unroll
            for (int r = 0; r < 4; ++r) {
                int row = m0 + wm + mi * 16 + rq + r;
                if (row >= M) continue;
                float v = acc[mi][ni][r] + bv;
                if (do_gelu) v = 0.5f * v * (1.0f + erff(v * 0.7071067811865475f));
                if (c_bf) ((unsigned short*)C)[(size_t)row * Nc + col] = f2bf(v);
                else      ((float*)C)[(size_t)row * Nc + col] = v;
            }
        }
    }
}

// ====== attention: block per node, wave per head; bf16 q/kv/ao ===============
__global__ __launch_bounds__(256) void attn_kernel(
    const unsigned short* __restrict__ q,    // [N, 256] bf16
    const unsigned short* __restrict__ kv,   // [N, 512] bf16 (k | v)
    const int* __restrict__ nbr,             // [N, KCAP]
    const int* __restrict__ cnt,             // [N]
    unsigned short* __restrict__ ao)         // [N, 256] bf16
{
    const int n    = blockIdx.x;
    const int tid  = threadIdx.x;
    const int h    = tid >> 6;
    const int lane = tid & 63;

    __shared__ float sc[NHEAD][KCAP];
    __shared__ int   nbs[KCAP];

    int deg = cnt[n];
    if (deg > KCAP) deg = KCAP;
    const bool iso = (deg == 0);
    if (iso) deg = 1;

    if (tid < KCAP)
        nbs[tid] = (tid < deg) ? (iso ? n : nbr[n * KCAP + tid]) : 0;
    __syncthreads();

    // ---- scores: 8 lane-groups of 8 (r3-proven structure) ----
    {
        const int sub = lane & 7;
        const int grp = lane >> 3;
        float qf[8];
        {
            uint4 qu = *(const uint4*)&q[(size_t)n * DIM + h * DHEAD + sub * 8];
            qf[0] = bflo(qu.x); qf[1] = bfhi(qu.x);
            qf[2] = bflo(qu.y); qf[3] = bfhi(qu.y);
            qf[4] = bflo(qu.z); qf[5] = bfhi(qu.z);
            qf[6] = bflo(qu.w); qf[7] = bfhi(qu.w);
        }
        const int nit = (deg + 7) >> 3;
        for (int it = 0; it < nit; ++it) {
            int j  = it * 8 + grp;
            int jc = (j < deg) ? j : (deg - 1);
            int nb = nbs[jc];
            uint4 ku = *(const uint4*)&kv[(size_t)nb * 512 + h * DHEAD + sub * 8];
            float p = qf[0] * bflo(ku.x);
            p = fmaf(qf[1], bfhi(ku.x), p);
            p = fmaf(qf[2], bflo(ku.y), p);
            p = fmaf(qf[3], bfhi(ku.y), p);
            p = fmaf(qf[4], bflo(ku.z), p);
            p = fmaf(qf[5], bfhi(ku.z), p);
            p = fmaf(qf[6], bflo(ku.w), p);
            p = fmaf(qf[7], bfhi(ku.w), p);
            p += __shfl_xor(p, 1, 64);
            p += __shfl_xor(p, 2, 64);
            p += __shfl_xor(p, 4, 64);
            if (sub == 0 && j < deg) sc[h][j] = p * 0.125f;   // 1/sqrt(64)
        }
    }
    __syncthreads();

    // ---- softmax over deg scores (per wave) ----
    {
        float s  = (lane < deg) ? sc[h][lane] : -1e30f;
        float mx = s;
#pragma unroll
        for (int m = 32; m >= 1; m >>= 1) mx = fmaxf(mx, __shfl_xor(mx, m, 64));
        float e   = (lane < deg) ? __expf(s - mx) : 0.0f;
        float sum = e;
#pragma unroll
        for (int m = 32; m >= 1; m >>= 1) sum += __shfl_xor(sum, m, 64);
        float inv = 1.0f / sum;
        if (lane < KCAP) sc[h][lane] = e * inv;
    }
    __syncthreads();

    // ---- PV: lane owns output dim (r3-proven serial loop), bf16 loads ----
    {
        float accv = 0.0f;
        for (int j = 0; j < deg; ++j) {
            int nb = nbs[j];
            float vx = bflo((unsigned)kv[(size_t)nb * 512 + 256 + h * DHEAD + lane]);
            accv = fmaf(sc[h][j], vx, accv);
        }
        ao[(size_t)n * DIM + h * DHEAD + lane] = f2bf(accv);
    }
}

// =============== fused residual-add + layernorm, wave per row (fp32) =========
__global__ __launch_bounds__(256) void ln_add_kernel(
    const float* __restrict__ xin, const float* __restrict__ t,
    const float* __restrict__ g, const float* __restrict__ b,
    float* __restrict__ xout)
{
    const int wave = threadIdx.x >> 6;
    const int lane = threadIdx.x & 63;
    const int row  = blockIdx.x * 4 + wave;

    float4 xv = *(const float4*)&xin[(size_t)row * DIM + lane * 4];
    float4 tv = *(const float4*)&t[(size_t)row * DIM + lane * 4];
    float v[4] = { xv.x + tv.x, xv.y + tv.y, xv.z + tv.z, xv.w + tv.w };
    float s = 0.f, ss = 0.f;
#pragma unroll
    for (int i = 0; i < 4; ++i) { s += v[i]; ss += v[i] * v[i]; }
#pragma unroll
    for (int m = 32; m >= 1; m >>= 1) {
        s  += __shfl_xor(s, m, 64);
        ss += __shfl_xor(ss, m, 64);
    }
    const float mu  = s * (1.0f / DIM);
    const float var = ss * (1.0f / DIM) - mu * mu;
    const float r   = rsqrtf(var + 1e-5f);
    float o[4];
#pragma unroll
    for (int i = 0; i < 4; ++i) {
        int c = lane * 4 + i;
        o[i] = (v[i] - mu) * r * g[c] + b[c];
    }
    *(float4*)&xout[(size_t)row * DIM + lane * 4] = make_float4(o[0], o[1], o[2], o[3]);
}

// =============== emit: fp32 x -> d_out in the detected dtype =================
__global__ void emit_kernel(const float* __restrict__ x, void* __restrict__ out,
                            const int* __restrict__ flag) {
    int i0 = (blockIdx.x * 256 + threadIdx.x) * 4;
    if (i0 >= N_NODES * DIM) return;
    float4 v = *(const float4*)(x + i0);
    if (flag[0]) {
        *(float4*)((float*)out + i0) = v;
    } else {
        ushort4 u;
        u.x = f2bf(v.x); u.y = f2bf(v.y); u.z = f2bf(v.z); u.w = f2bf(v.w);
        *(ushort4*)((unsigned short*)out + i0) = u;
    }
}

// =============== launch ======================================================
extern "C" void kernel_launch(void* const* d_in, const int* in_sizes, int n_in,
                              void* d_out, int out_size, void* d_ws, size_t ws_size,
                              hipStream_t stream) {
    const int* ei = (const int*)d_in[14];

    char* ws = (char*)d_ws;
    size_t off = 0;
    auto alloc = [&](size_t bytes) -> void* {
        void* p = ws + off;
        off = (off + bytes + 255) & ~(size_t)255;
        return p;
    };

    // fp32 canon: expr(0), in_proj_b(3), out_proj_b(5), ffn_b1(7), ffn_b2(9),
    //             ln1_g(10), ln1_b(11), ln2_g(12), ln2_b(13)
    const int fidx[9] = { 0, 3, 5, 7, 9, 10, 11, 12, 13 };
    const int fn[9]   = { N_NODES * DIM, NLAYER * 3 * DIM, NLAYER * DIM,
                          NLAYER * 2 * DIM, NLAYER * DIM,
                          NLAYER * DIM, NLAYER * DIM, NLAYER * DIM, NLAYER * DIM };
    ConvF32Args cf;
    float* canf[9];
    for (int i = 0; i < 9; ++i) {
        canf[i] = (float*)alloc((size_t)fn[i] * 4);
        cf.src[i] = d_in[fidx[i]];
        cf.dst[i] = canf[i];
        cf.n[i]   = fn[i];
    }

    // bf16 canon: spatial(1), in_proj_w(2), out_proj_w(4), ffn_w1(6), ffn_w2(8)
    const int bidx[5] = { 1, 2, 4, 6, 8 };
    const int bn[5]   = { N_NODES * DIM, NLAYER * 3 * DIM * DIM, NLAYER * DIM * DIM,
                          NLAYER * 2 * DIM * DIM, NLAYER * DIM * 2 * DIM };
    ConvBfArgs cb;
    unsigned short* canb[5];
    for (int i = 0; i < 5; ++i) {
        canb[i] = (unsigned short*)alloc((size_t)bn[i] * 2);
        cb.src[i] = d_in[bidx[i]];
        cb.dst[i] = canb[i];
        cb.n[i]   = bn[i];
    }

    const float* expr_f          = canf[0];
    const unsigned short* spat_b = canb[0];
    const unsigned short* ipw    = canb[1];
    const unsigned short* opw    = canb[2];
    const unsigned short* w1     = canb[3];
    const unsigned short* w2     = canb[4];

    float*          x_buf  = (float*)alloc((size_t)N_NODES * DIM * 4);
    unsigned short* q_buf  = (unsigned short*)alloc((size_t)N_NODES * DIM * 2);
    unsigned short* kv_buf = (unsigned short*)alloc((size_t)N_NODES * 2 * DIM * 2);
    unsigned short* ao_buf = (unsigned short*)alloc((size_t)N_NODES * DIM * 2);
    unsigned short* h_buf  = (unsigned short*)alloc((size_t)N_NODES * 2 * DIM * 2);
    float*          t_buf  = (float*)alloc((size_t)N_NODES * DIM * 4);
    int* cnt  = (int*)alloc((size_t)N_NODES * 4);
    int* nbr  = (int*)alloc((size_t)N_NODES * KCAP * 4);
    int* flag = (int*)alloc(256);

    sniff_kernel<<<1, 256, 0, stream>>>((const unsigned short*)d_in[0], flag);
    {
        int maxb = (fn[0] + 1023) / 1024;
        conv_f32_kernel<<<dim3(maxb, 9), 256, 0, stream>>>(cf, flag);
        conv_bf16_kernel<<<dim3(maxb, 5), 256, 0, stream>>>(cb, flag);
    }
    zero_cnt_kernel<<<(N_NODES + 255) / 256, 256, 0, stream>>>(cnt);
    build_nbr_kernel<<<(NEDGE + 255) / 256, 256, 0, stream>>>(ei, cnt, nbr);

    for (int i = 0; i < NLAYER; ++i) {
        const unsigned short* Wqkv = ipw + (size_t)i * 3 * DIM * DIM;
        const float*          bqkv = canf[1] + (size_t)i * 3 * DIM;
        const float* xin = (i == 0) ? expr_f : x_buf;

        // q = x @ Wq^T + bq      (A fp32 -> C bf16)
        gemm_kernel<<<dim3(NBM, 2), 256, 0, stream>>>(
            xin, Wqkv, bqkv, q_buf, N_NODES, DIM, DIM, 0, 1, 0);
        // kv = spat @ [Wk;Wv]^T  (A bf16 -> C bf16)
        gemm_kernel<<<dim3(NBM, 4), 256, 0, stream>>>(
            spat_b, Wqkv + (size_t)DIM * DIM, bqkv + DIM, kv_buf,
            N_NODES, 2 * DIM, DIM, 1, 1, 0);
        // attention (bf16)
        attn_kernel<<<N_NODES, 256, 0, stream>>>(q_buf, kv_buf, nbr, cnt, ao_buf);
        // t = ao @ Wo^T + bo     (A bf16 -> C fp32)
        gemm_kernel<<<dim3(NBM, 2), 256, 0, stream>>>(
            ao_buf, opw + (size_t)i * DIM * DIM, canf[2] + (size_t)i * DIM,
            t_buf, N_NODES, DIM, DIM, 1, 0, 0);
        // x = LN(xin + t)
        ln_add_kernel<<<N_NODES / 4, 256, 0, stream>>>(
            xin, t_buf, canf[5] + (size_t)i * DIM, canf[6] + (size_t)i * DIM, x_buf);
        // h = gelu(x @ W1^T + b1)  (A fp32 -> C bf16)
        gemm_kernel<<<dim3(NBM, 4), 256, 0, stream>>>(
            x_buf, w1 + (size_t)i * 2 * DIM * DIM, canf[3] + (size_t)i * 2 * DIM,
            h_buf, N_NODES, 2 * DIM, DIM, 0, 1, 1);
        // t = h @ W2^T + b2      (A bf16 -> C fp32)
        gemm_kernel<<<dim3(NBM, 2), 256, 0, stream>>>(
            h_buf, w2 + (size_t)i * DIM * 2 * DIM, canf[4] + (size_t)i * DIM,
            t_buf, N_NODES, DIM, 2 * DIM, 1, 0, 0);
        // x = LN(x + t)
        ln_add_kernel<<<N_NODES / 4, 256, 0, stream>>>(
            x_buf, t_buf, canf[7] + (size_t)i * DIM, canf[8] + (size_t)i * DIM, x_buf);
    }

    emit_kernel<<<(N_NODES * DIM) / 1024, 256, 0, stream>>>(x_buf, d_out, flag);
}

// Round 8
// 482.587 us; speedup vs baseline: 2.5681x; 1.2730x over previous
//
#include <hip/hip_runtime.h>

#define N_NODES 20000
#define DIM 256
#define NHEAD 4
#define DHEAD 64
#define NLAYER 2
#define NEDGE 320000
#define KCAP 48
#define NBM64 313   // ceil(20000/64)

typedef __bf16 v8bf __attribute__((ext_vector_type(8)));
typedef float v4f __attribute__((ext_vector_type(4)));

union LU { uint4 u; v8bf v; };

__device__ __forceinline__ unsigned short f2bf(float f) {
    unsigned u = __float_as_uint(f);
    unsigned r = u + 0x7FFFu + ((u >> 16) & 1u);   // RNE
    return (unsigned short)(r >> 16);
}
__device__ __forceinline__ float bflo(unsigned u) { return __uint_as_float(u << 16); }
__device__ __forceinline__ float bfhi(unsigned u) { return __uint_as_float(u & 0xFFFF0000u); }

// =============== dtype sniffer: 1 => inputs are float32, 0 => bf16 ===========
__global__ void sniff_kernel(const unsigned short* __restrict__ p,
                             int* __restrict__ flag) {
    __shared__ int s;
    if (threadIdx.x == 0) s = 0;
    __syncthreads();
    int c = 0;
    for (int i = threadIdx.x; i < 4096; i += 256) {
        unsigned short u = p[i];
        unsigned e = (u >> 7) & 0xFFu;
        if (e == 0xFFu) c++;
        else if (e == 0u && (u & 0x7Fu)) c++;
    }
    atomicAdd(&s, c);
    __syncthreads();
    if (threadIdx.x == 0) flag[0] = (s >= 4) ? 1 : 0;
}

// ===== conv to bf16 canon: generic multi-tensor (embeds / weights) ===========
struct ConvBfArgs { const void* src[4]; unsigned short* dst[4]; int n[4]; };

__global__ void conv_bf16_kernel(ConvBfArgs a, const int* __restrict__ flag) {
    const int t  = blockIdx.y;
    const int n  = a.n[t];
    const int i0 = (blockIdx.x * 256 + threadIdx.x) * 4;
    if (i0 >= n) return;
    unsigned short* dst = a.dst[t];
    if (flag[0]) {
        float4 v = *(const float4*)((const float*)a.src[t] + i0);
        ushort4 o;
        o.x = f2bf(v.x); o.y = f2bf(v.y); o.z = f2bf(v.z); o.w = f2bf(v.w);
        *(ushort4*)(dst + i0) = o;
    } else {
        ushort4 u = *(const ushort4*)((const unsigned short*)a.src[t] + i0);
        *(ushort4*)(dst + i0) = u;
    }
}

// ===== conv to fp32 canon: biases + LN params (8 small tensors) ==============
struct ConvF32Args { const void* src[8]; float* dst[8]; int n[8]; };

__global__ void conv_f32_kernel(ConvF32Args a, const int* __restrict__ flag) {
    const int t  = blockIdx.y;
    const int n  = a.n[t];
    const int i0 = (blockIdx.x * 256 + threadIdx.x) * 4;
    if (i0 >= n) return;
    float* dst = a.dst[t];
    if (flag[0]) {
        float4 v = *(const float4*)((const float*)a.src[t] + i0);
        *(float4*)(dst + i0) = v;
    } else {
        ushort4 u = *(const ushort4*)((const unsigned short*)a.src[t] + i0);
        *(float4*)(dst + i0) = make_float4(bflo(u.x), bflo(u.y), bflo(u.z), bflo(u.w));
    }
}

// =============== neighbor build ==============================================
__global__ void zero_cnt_kernel(int* __restrict__ cnt) {
    int i = blockIdx.x * 256 + threadIdx.x;
    if (i < N_NODES) cnt[i] = 0;
}

__global__ void build_nbr_kernel(const int* __restrict__ ei,
                                 int* __restrict__ cnt, int* __restrict__ nbr) {
    int e = blockIdx.x * 256 + threadIdx.x;
    if (e >= NEDGE) return;
    int s = ei[e];
    int t = ei[NEDGE + e];
    int slot = atomicAdd(&cnt[t], 1);
    if (slot < KCAP) nbr[t * KCAP + slot] = s;
}

// ==== MFMA GEMM: C[M,Nc] = A[M,K] @ B[Nc,K]^T + bias (+gelu), all bf16 =======
// Tile 64x128 (TM=64): grid (NBM64, Nc/128); 4 waves, each 64x32 (acc 4x2).
__global__ __launch_bounds__(256) void gemm_kernel(
    const unsigned short* __restrict__ A, const unsigned short* __restrict__ B,
    const float* __restrict__ bias, unsigned short* __restrict__ C,
    int M, int Nc, int Kd, int do_gelu)
{
    __shared__ __align__(16) __bf16 As[64][72];
    __shared__ __align__(16) __bf16 Bs[128][72];
    const int tid  = threadIdx.x;
    const int m0   = blockIdx.x * 64;
    const int n0   = blockIdx.y * 128;
    const int wave = tid >> 6;
    const int lane = tid & 63;
    const int wn0  = wave * 32;
    const int lm   = lane & 15;
    const int lk   = (lane >> 4) * 8;

    v4f acc[4][2] = {};

    for (int k0 = 0; k0 < Kd; k0 += 64) {
#pragma unroll
        for (int i = 0; i < 2; ++i) {
            int c   = tid + i * 256;
            int row = c >> 3;
            int col = (c & 7) << 3;
            uint4 u = make_uint4(0u, 0u, 0u, 0u);
            if (m0 + row < M)
                u = *(const uint4*)&A[(size_t)(m0 + row) * Kd + k0 + col];
            LU ta; ta.u = u;
            *(v8bf*)&As[row][col] = ta.v;
        }
#pragma unroll
        for (int i = 0; i < 4; ++i) {
            int c   = tid + i * 256;
            int row = c >> 3;
            int col = (c & 7) << 3;
            LU tb; tb.u = *(const uint4*)&B[(size_t)(n0 + row) * Kd + k0 + col];
            *(v8bf*)&Bs[row][col] = tb.v;
        }
        __syncthreads();
#pragma unroll
        for (int ks = 0; ks < 2; ++ks) {
            v8bf af[4], bq[2];
#pragma unroll
            for (int mi = 0; mi < 4; ++mi)
                af[mi] = *(const v8bf*)&As[mi * 16 + lm][ks * 32 + lk];
#pragma unroll
            for (int ni = 0; ni < 2; ++ni)
                bq[ni] = *(const v8bf*)&Bs[wn0 + ni * 16 + lm][ks * 32 + lk];
#pragma unroll
            for (int mi = 0; mi < 4; ++mi)
#pragma unroll
                for (int ni = 0; ni < 2; ++ni)
                    acc[mi][ni] = __builtin_amdgcn_mfma_f32_16x16x32_bf16(
                        af[mi], bq[ni], acc[mi][ni], 0, 0, 0);
        }
        __syncthreads();
    }

    // D layout: col = lane&15, row = (lane>>4)*4 + r  (m89-verified)
    const int rq = (lane >> 4) << 2;
#pragma unroll
    for (int ni = 0; ni < 2; ++ni) {
        int col  = n0 + wn0 + ni * 16 + lm;
        float bv = bias[col];
#pragma unroll
        for (int mi = 0; mi < 4; ++mi) {
#pragma unroll
            for (int r = 0; r < 4; ++r) {
                int row = m0 + mi * 16 + rq + r;
                if (row >= M) continue;
                float v = acc[mi][ni][r] + bv;
                if (do_gelu) v = 0.5f * v * (1.0f + erff(v * 0.7071067811865475f));
                C[(size_t)row * Nc + col] = f2bf(v);
            }
        }
    }
}

// ====== attention: block per node, wave per head; bf16 q/kv/ao ===============
__global__ __launch_bounds__(256) void attn_kernel(
    const unsigned short* __restrict__ q,    // [N, 256]
    const unsigned short* __restrict__ kv,   // [N, 512] (k | v)
    const int* __restrict__ nbr,             // [N, KCAP]
    const int* __restrict__ cnt,             // [N]
    unsigned short* __restrict__ ao)         // [N, 256]
{
    const int n    = blockIdx.x;
    const int tid  = threadIdx.x;
    const int h    = tid >> 6;
    const int lane = tid & 63;

    __shared__ float sc[NHEAD][KCAP];
    __shared__ int   nbs[KCAP];

    int deg = cnt[n];
    if (deg > KCAP) deg = KCAP;
    const bool iso = (deg == 0);
    if (iso) deg = 1;

    if (tid < KCAP)
        nbs[tid] = (tid < deg) ? (iso ? n : nbr[n * KCAP + tid]) : 0;
    __syncthreads();

    // ---- scores: 8 lane-groups of 8 ----
    {
        const int sub = lane & 7;
        const int grp = lane >> 3;
        float qf[8];
        {
            uint4 qu = *(const uint4*)&q[(size_t)n * DIM + h * DHEAD + sub * 8];
            qf[0] = bflo(qu.x); qf[1] = bfhi(qu.x);
            qf[2] = bflo(qu.y); qf[3] = bfhi(qu.y);
            qf[4] = bflo(qu.z); qf[5] = bfhi(qu.z);
            qf[6] = bflo(qu.w); qf[7] = bfhi(qu.w);
        }
        const int nit = (deg + 7) >> 3;
        for (int it = 0; it < nit; ++it) {
            int j  = it * 8 + grp;
            int jc = (j < deg) ? j : (deg - 1);
            int nb = nbs[jc];
            uint4 ku = *(const uint4*)&kv[(size_t)nb * 512 + h * DHEAD + sub * 8];
            float p = qf[0] * bflo(ku.x);
            p = fmaf(qf[1], bfhi(ku.x), p);
            p = fmaf(qf[2], bflo(ku.y), p);
            p = fmaf(qf[3], bfhi(ku.y), p);
            p = fmaf(qf[4], bflo(ku.z), p);
            p = fmaf(qf[5], bfhi(ku.z), p);
            p = fmaf(qf[6], bflo(ku.w), p);
            p = fmaf(qf[7], bfhi(ku.w), p);
            p += __shfl_xor(p, 1, 64);
            p += __shfl_xor(p, 2, 64);
            p += __shfl_xor(p, 4, 64);
            if (sub == 0 && j < deg) sc[h][j] = p * 0.125f;   // 1/sqrt(64)
        }
    }
    __syncthreads();

    // ---- softmax over deg scores (per wave) ----
    {
        float s  = (lane < deg) ? sc[h][lane] : -1e30f;
        float mx = s;
#pragma unroll
        for (int m = 32; m >= 1; m >>= 1) mx = fmaxf(mx, __shfl_xor(mx, m, 64));
        float e   = (lane < deg) ? __expf(s - mx) : 0.0f;
        float sum = e;
#pragma unroll
        for (int m = 32; m >= 1; m >>= 1) sum += __shfl_xor(sum, m, 64);
        float inv = 1.0f / sum;
        if (lane < KCAP) sc[h][lane] = e * inv;
    }
    __syncthreads();

    // ---- PV: 4 lane-quarters of 16; 4 neighbors/iter, 4 dims/lane ----
    {
        const int quarter = lane >> 4;
        const int d0      = (lane & 15) * 4;
        float a0 = 0.f, a1 = 0.f, a2 = 0.f, a3 = 0.f;
        for (int j = 0; j < deg; j += 4) {
            int j0 = j + quarter;
            int jc = (j0 < deg) ? j0 : (deg - 1);
            int nb = nbs[jc];
            uint2 u = *(const uint2*)&kv[(size_t)nb * 512 + 256 + h * DHEAD + d0];
            float w = (j0 < deg) ? sc[h][j0] : 0.f;
            a0 = fmaf(w, bflo(u.x), a0);
            a1 = fmaf(w, bfhi(u.x), a1);
            a2 = fmaf(w, bflo(u.y), a2);
            a3 = fmaf(w, bfhi(u.y), a3);
        }
        a0 += __shfl_xor(a0, 16, 64); a0 += __shfl_xor(a0, 32, 64);
        a1 += __shfl_xor(a1, 16, 64); a1 += __shfl_xor(a1, 32, 64);
        a2 += __shfl_xor(a2, 16, 64); a2 += __shfl_xor(a2, 32, 64);
        a3 += __shfl_xor(a3, 16, 64); a3 += __shfl_xor(a3, 32, 64);
        if (lane < 16) {
            uint2 o;
            o.x = (unsigned)f2bf(a0) | ((unsigned)f2bf(a1) << 16);
            o.y = (unsigned)f2bf(a2) | ((unsigned)f2bf(a3) << 16);
            *(uint2*)&ao[(size_t)n * DIM + h * DHEAD + d0] = o;
        }
    }
}

// ===== fused residual-add + layernorm, wave per row; bf16 I/O, fp32 math =====
// final=1: write d_out (fp32 or bf16 per flag); else write xout (bf16).
__global__ __launch_bounds__(256) void ln_add_kernel(
    const unsigned short* __restrict__ x, const unsigned short* __restrict__ t,
    const float* __restrict__ g, const float* __restrict__ b,
    unsigned short* __restrict__ xout, void* __restrict__ dout,
    int final_out, const int* __restrict__ flag)
{
    const int wave = threadIdx.x >> 6;
    const int lane = threadIdx.x & 63;
    const int row  = blockIdx.x * 4 + wave;   // grid = N/4

    const ushort4 xu = *(const ushort4*)&x[(size_t)row * DIM + lane * 4];
    const ushort4 tu = *(const ushort4*)&t[(size_t)row * DIM + lane * 4];
    float v[4];
    v[0] = bflo(xu.x) + bflo(tu.x);
    v[1] = bflo(xu.y) + bflo(tu.y);
    v[2] = bflo(xu.z) + bflo(tu.z);
    v[3] = bflo(xu.w) + bflo(tu.w);

    float s = 0.f, ss = 0.f;
#pragma unroll
    for (int i = 0; i < 4; ++i) { s += v[i]; ss += v[i] * v[i]; }
#pragma unroll
    for (int m = 32; m >= 1; m >>= 1) {
        s  += __shfl_xor(s, m, 64);
        ss += __shfl_xor(ss, m, 64);
    }
    const float mu  = s * (1.0f / DIM);
    const float var = ss * (1.0f / DIM) - mu * mu;
    const float r   = rsqrtf(var + 1e-5f);

    float o[4];
#pragma unroll
    for (int i = 0; i < 4; ++i) {
        int c = lane * 4 + i;
        o[i] = (v[i] - mu) * r * g[c] + b[c];
    }
    if (final_out) {
        if (flag[0]) {
            *(float4*)&((float*)dout)[(size_t)row * DIM + lane * 4] =
                make_float4(o[0], o[1], o[2], o[3]);
        } else {
            ushort4 u;
            u.x = f2bf(o[0]); u.y = f2bf(o[1]); u.z = f2bf(o[2]); u.w = f2bf(o[3]);
            *(ushort4*)&((unsigned short*)dout)[(size_t)row * DIM + lane * 4] = u;
        }
    } else {
        ushort4 u;
        u.x = f2bf(o[0]); u.y = f2bf(o[1]); u.z = f2bf(o[2]); u.w = f2bf(o[3]);
        *(ushort4*)&xout[(size_t)row * DIM + lane * 4] = u;
    }
}

// =============== launch ======================================================
extern "C" void kernel_launch(void* const* d_in, const int* in_sizes, int n_in,
                              void* d_out, int out_size, void* d_ws, size_t ws_size,
                              hipStream_t stream) {
    const int* ei = (const int*)d_in[14];

    char* ws = (char*)d_ws;
    size_t off = 0;
    auto alloc = [&](size_t bytes) -> void* {
        void* p = ws + off;
        off = (off + bytes + 255) & ~(size_t)255;
        return p;
    };

    // bf16 canon group A (embeds): expr(0), spatial(1)
    ConvBfArgs ce;
    unsigned short* expr_b = (unsigned short*)alloc((size_t)N_NODES * DIM * 2);
    unsigned short* spat_b = (unsigned short*)alloc((size_t)N_NODES * DIM * 2);
    ce.src[0] = d_in[0]; ce.dst[0] = expr_b; ce.n[0] = N_NODES * DIM;
    ce.src[1] = d_in[1]; ce.dst[1] = spat_b; ce.n[1] = N_NODES * DIM;
    ce.src[2] = d_in[0]; ce.dst[2] = expr_b; ce.n[2] = 0;
    ce.src[3] = d_in[0]; ce.dst[3] = expr_b; ce.n[3] = 0;

    // bf16 canon group B (weights): in_proj_w(2), out_proj_w(4), ffn_w1(6), ffn_w2(8)
    const int widx[4] = { 2, 4, 6, 8 };
    const int wn[4]   = { NLAYER * 3 * DIM * DIM, NLAYER * DIM * DIM,
                          NLAYER * 2 * DIM * DIM, NLAYER * DIM * 2 * DIM };
    ConvBfArgs cw;
    unsigned short* canw[4];
    for (int i = 0; i < 4; ++i) {
        canw[i] = (unsigned short*)alloc((size_t)wn[i] * 2);
        cw.src[i] = d_in[widx[i]];
        cw.dst[i] = canw[i];
        cw.n[i]   = wn[i];
    }
    const unsigned short* ipw = canw[0];
    const unsigned short* opw = canw[1];
    const unsigned short* w1  = canw[2];
    const unsigned short* w2  = canw[3];

    // fp32 canon: in_proj_b(3), out_proj_b(5), ffn_b1(7), ffn_b2(9), ln1g..ln2b(10..13)
    const int fidx[8] = { 3, 5, 7, 9, 10, 11, 12, 13 };
    const int fn[8]   = { NLAYER * 3 * DIM, NLAYER * DIM, NLAYER * 2 * DIM,
                          NLAYER * DIM, NLAYER * DIM, NLAYER * DIM,
                          NLAYER * DIM, NLAYER * DIM };
    ConvF32Args cf;
    float* canf[8];
    for (int i = 0; i < 8; ++i) {
        canf[i] = (float*)alloc((size_t)fn[i] * 4);
        cf.src[i] = d_in[fidx[i]];
        cf.dst[i] = canf[i];
        cf.n[i]   = fn[i];
    }

    unsigned short* x_buf  = (unsigned short*)alloc((size_t)N_NODES * DIM * 2);
    unsigned short* q_buf  = (unsigned short*)alloc((size_t)N_NODES * DIM * 2);
    unsigned short* kv_buf = (unsigned short*)alloc((size_t)N_NODES * 2 * DIM * 2);
    unsigned short* ao_buf = (unsigned short*)alloc((size_t)N_NODES * DIM * 2);
    unsigned short* h_buf  = (unsigned short*)alloc((size_t)N_NODES * 2 * DIM * 2);
    unsigned short* t_buf  = (unsigned short*)alloc((size_t)N_NODES * DIM * 2);
    int* cnt  = (int*)alloc((size_t)N_NODES * 4);
    int* nbr  = (int*)alloc((size_t)N_NODES * KCAP * 4);
    int* flag = (int*)alloc(256);

    sniff_kernel<<<1, 256, 0, stream>>>((const unsigned short*)d_in[0], flag);
    conv_bf16_kernel<<<dim3((N_NODES * DIM) / 1024, 2), 256, 0, stream>>>(ce, flag);
    conv_bf16_kernel<<<dim3((wn[0] + 1023) / 1024, 4), 256, 0, stream>>>(cw, flag);
    conv_f32_kernel<<<dim3(2, 8), 256, 0, stream>>>(cf, flag);
    zero_cnt_kernel<<<(N_NODES + 255) / 256, 256, 0, stream>>>(cnt);
    build_nbr_kernel<<<(NEDGE + 255) / 256, 256, 0, stream>>>(ei, cnt, nbr);

    for (int i = 0; i < NLAYER; ++i) {
        const unsigned short* Wqkv = ipw + (size_t)i * 3 * DIM * DIM;
        const float*          bqkv = canf[0] + (size_t)i * 3 * DIM;
        const unsigned short* xin  = (i == 0) ? expr_b : x_buf;

        // q = x @ Wq^T + bq
        gemm_kernel<<<dim3(NBM64, 2), 256, 0, stream>>>(
            xin, Wqkv, bqkv, q_buf, N_NODES, DIM, DIM, 0);
        // kv = spat @ [Wk;Wv]^T + [bk;bv]
        gemm_kernel<<<dim3(NBM64, 4), 256, 0, stream>>>(
            spat_b, Wqkv + (size_t)DIM * DIM, bqkv + DIM, kv_buf,
            N_NODES, 2 * DIM, DIM, 0);
        // attention
        attn_kernel<<<N_NODES, 256, 0, stream>>>(q_buf, kv_buf, nbr, cnt, ao_buf);
        // t = ao @ Wo^T + bo
        gemm_kernel<<<dim3(NBM64, 2), 256, 0, stream>>>(
            ao_buf, opw + (size_t)i * DIM * DIM, canf[1] + (size_t)i * DIM,
            t_buf, N_NODES, DIM, DIM, 0);
        // x = LN(xin + t)
        ln_add_kernel<<<N_NODES / 4, 256, 0, stream>>>(
            xin, t_buf, canf[4] + (size_t)i * DIM, canf[5] + (size_t)i * DIM,
            x_buf, nullptr, 0, flag);
        // h = gelu(x @ W1^T + b1)
        gemm_kernel<<<dim3(NBM64, 4), 256, 0, stream>>>(
            x_buf, w1 + (size_t)i * 2 * DIM * DIM, canf[2] + (size_t)i * 2 * DIM,
            h_buf, N_NODES, 2 * DIM, DIM, 1);
        // t = h @ W2^T + b2
        gemm_kernel<<<dim3(NBM64, 2), 256, 0, stream>>>(
            h_buf, w2 + (size_t)i * DIM * 2 * DIM, canf[3] + (size_t)i * DIM,
            t_buf, N_NODES, DIM, 2 * DIM, 0);
        // x = LN(x + t); final layer writes d_out (flag-gated dtype)
        ln_add_kernel<<<N_NODES / 4, 256, 0, stream>>>(
            x_buf, t_buf, canf[6] + (size_t)i * DIM, canf[7] + (size_t)i * DIM,
            x_buf, d_out, (i == NLAYER - 1) ? 1 : 0, flag);
    }
}

// Round 9
// 449.395 us; speedup vs baseline: 2.7578x; 1.0739x over previous
//
#include <hip/hip_runtime.h>

#define N_NODES 20000
#define DIM 256
#define NHEAD 4
#define DHEAD 64
#define NLAYER 2
#define NEDGE 320000
#define KCAP 48
#define NBM64 313   // ceil(20000/64)

typedef __bf16 v8bf __attribute__((ext_vector_type(8)));
typedef float v4f __attribute__((ext_vector_type(4)));

union LU { uint4 u; v8bf v; };

__device__ __forceinline__ unsigned short f2bf(float f) {
    unsigned u = __float_as_uint(f);
    unsigned r = u + 0x7FFFu + ((u >> 16) & 1u);   // RNE
    return (unsigned short)(r >> 16);
}
__device__ __forceinline__ float bflo(unsigned u) { return __uint_as_float(u << 16); }
__device__ __forceinline__ float bfhi(unsigned u) { return __uint_as_float(u & 0xFFFF0000u); }

// =============== dtype sniffer: 1 => inputs are float32, 0 => bf16 ===========
__global__ void sniff_kernel(const unsigned short* __restrict__ p,
                             int* __restrict__ flag) {
    __shared__ int s;
    if (threadIdx.x == 0) s = 0;
    __syncthreads();
    int c = 0;
    for (int i = threadIdx.x; i < 4096; i += 256) {
        unsigned short u = p[i];
        unsigned e = (u >> 7) & 0xFFu;
        if (e == 0xFFu) c++;
        else if (e == 0u && (u & 0x7Fu)) c++;
    }
    atomicAdd(&s, c);
    __syncthreads();
    if (threadIdx.x == 0) flag[0] = (s >= 4) ? 1 : 0;
}

// ===== conv to bf16 canon: 6 tensors (embeds + weights) ======================
struct ConvBfArgs { const void* src[6]; unsigned short* dst[6]; int n[6]; };

__global__ void conv_bf16_kernel(ConvBfArgs a, const int* __restrict__ flag) {
    const int t  = blockIdx.y;
    const int n  = a.n[t];
    const int i0 = (blockIdx.x * 256 + threadIdx.x) * 4;
    if (i0 >= n) return;
    unsigned short* dst = a.dst[t];
    if (flag[0]) {
        float4 v = *(const float4*)((const float*)a.src[t] + i0);
        ushort4 o;
        o.x = f2bf(v.x); o.y = f2bf(v.y); o.z = f2bf(v.z); o.w = f2bf(v.w);
        *(ushort4*)(dst + i0) = o;
    } else {
        ushort4 u = *(const ushort4*)((const unsigned short*)a.src[t] + i0);
        *(ushort4*)(dst + i0) = u;
    }
}

// ===== conv to fp32 canon: biases + LN params (8 small tensors) ==============
struct ConvF32Args { const void* src[8]; float* dst[8]; int n[8]; };

__global__ void conv_f32_kernel(ConvF32Args a, const int* __restrict__ flag) {
    const int t  = blockIdx.y;
    const int n  = a.n[t];
    const int i0 = (blockIdx.x * 256 + threadIdx.x) * 4;
    if (i0 >= n) return;
    float* dst = a.dst[t];
    if (flag[0]) {
        float4 v = *(const float4*)((const float*)a.src[t] + i0);
        *(float4*)(dst + i0) = v;
    } else {
        ushort4 u = *(const ushort4*)((const unsigned short*)a.src[t] + i0);
        *(float4*)(dst + i0) = make_float4(bflo(u.x), bflo(u.y), bflo(u.z), bflo(u.w));
    }
}

// =============== neighbor build ==============================================
__global__ void zero_cnt_kernel(int* __restrict__ cnt) {
    int i = blockIdx.x * 256 + threadIdx.x;
    if (i < N_NODES) cnt[i] = 0;
}

__global__ void build_nbr_kernel(const int* __restrict__ ei,
                                 int* __restrict__ cnt, int* __restrict__ nbr) {
    int e = blockIdx.x * 256 + threadIdx.x;
    if (e >= NEDGE) return;
    int s = ei[e];
    int t = ei[NEDGE + e];
    int slot = atomicAdd(&cnt[t], 1);
    if (slot < KCAP) nbr[t * KCAP + slot] = s;
}

// ==== MFMA GEMM body: 64x128 tile, register-prefetch pipelined K-loop ========
// C[M,Nc] tile at (m0, nC); B rows at nB (bias indexed by nB+col).
__device__ __forceinline__ void gemm_body(
    __bf16 (*As)[72], __bf16 (*Bs)[72],
    const unsigned short* __restrict__ A, const unsigned short* __restrict__ B,
    const float* __restrict__ bias, unsigned short* __restrict__ C,
    int M, int Nc, int Kd, int m0, int nB, int nC, int do_gelu)
{
    const int tid  = threadIdx.x;
    const int wave = tid >> 6;
    const int lane = tid & 63;
    const int wn0  = wave * 32;
    const int lm   = lane & 15;
    const int lk   = (lane >> 4) * 8;
    const int srow = tid >> 3;            // 0..31
    const int scol = (tid & 7) << 3;      // 0..56

    uint4 pa[2], pb[4];
#pragma unroll
    for (int i = 0; i < 2; ++i) {
        int row = srow + i * 32;
        pa[i] = make_uint4(0u, 0u, 0u, 0u);
        if (m0 + row < M)
            pa[i] = *(const uint4*)&A[(size_t)(m0 + row) * Kd + scol];
    }
#pragma unroll
    for (int i = 0; i < 4; ++i) {
        int row = srow + i * 32;
        pb[i] = *(const uint4*)&B[(size_t)(nB + row) * Kd + scol];
    }

    v4f acc[4][2] = {};

    for (int k0 = 0; k0 < Kd; k0 += 64) {
#pragma unroll
        for (int i = 0; i < 2; ++i) { LU t; t.u = pa[i]; *(v8bf*)&As[srow + i * 32][scol] = t.v; }
#pragma unroll
        for (int i = 0; i < 4; ++i) { LU t; t.u = pb[i]; *(v8bf*)&Bs[srow + i * 32][scol] = t.v; }
        __syncthreads();

        const int kn = k0 + 64;
        if (kn < Kd) {   // prefetch next tile; overlaps with MFMA below
#pragma unroll
            for (int i = 0; i < 2; ++i) {
                int row = srow + i * 32;
                pa[i] = make_uint4(0u, 0u, 0u, 0u);
                if (m0 + row < M)
                    pa[i] = *(const uint4*)&A[(size_t)(m0 + row) * Kd + kn + scol];
            }
#pragma unroll
            for (int i = 0; i < 4; ++i) {
                int row = srow + i * 32;
                pb[i] = *(const uint4*)&B[(size_t)(nB + row) * Kd + kn + scol];
            }
        }

#pragma unroll
        for (int ks = 0; ks < 2; ++ks) {
            v8bf af[4], bq[2];
#pragma unroll
            for (int mi = 0; mi < 4; ++mi)
                af[mi] = *(const v8bf*)&As[mi * 16 + lm][ks * 32 + lk];
#pragma unroll
            for (int ni = 0; ni < 2; ++ni)
                bq[ni] = *(const v8bf*)&Bs[wn0 + ni * 16 + lm][ks * 32 + lk];
#pragma unroll
            for (int mi = 0; mi < 4; ++mi)
#pragma unroll
                for (int ni = 0; ni < 2; ++ni)
                    acc[mi][ni] = __builtin_amdgcn_mfma_f32_16x16x32_bf16(
                        af[mi], bq[ni], acc[mi][ni], 0, 0, 0);
        }
        __syncthreads();
    }

    // D layout: col = lane&15, row = (lane>>4)*4 + r  (m89-verified)
    const int rq = (lane >> 4) << 2;
#pragma unroll
    for (int ni = 0; ni < 2; ++ni) {
        int colb = wn0 + ni * 16 + lm;
        float bv = bias[nB + colb];
        int colc = nC + colb;
#pragma unroll
        for (int mi = 0; mi < 4; ++mi) {
#pragma unroll
            for (int r = 0; r < 4; ++r) {
                int row = m0 + mi * 16 + rq + r;
                if (row >= M) continue;
                float v = acc[mi][ni][r] + bv;
                if (do_gelu) v = 0.5f * v * (1.0f + erff(v * 0.7071067811865475f));
                C[(size_t)row * Nc + colc] = f2bf(v);
            }
        }
    }
}

// Generic GEMM: grid (ceil(M/64), Nc/128)
__global__ __launch_bounds__(256) void gemm_kernel(
    const unsigned short* __restrict__ A, const unsigned short* __restrict__ B,
    const float* __restrict__ bias, unsigned short* __restrict__ C,
    int M, int Nc, int Kd, int do_gelu)
{
    __shared__ __align__(16) __bf16 As[64][72];
    __shared__ __align__(16) __bf16 Bs[128][72];
    const int n0 = blockIdx.y * 128;
    gemm_body(As, Bs, A, B, bias, C, M, Nc, Kd, blockIdx.x * 64, n0, n0, do_gelu);
}

// Fused q+kv projection: grid (ceil(M/64), 6); y<2 -> q from x, y>=2 -> kv from spat
__global__ __launch_bounds__(256) void qkv_kernel(
    const unsigned short* __restrict__ x, const unsigned short* __restrict__ spat,
    const unsigned short* __restrict__ W, const float* __restrict__ bias,
    unsigned short* __restrict__ q, unsigned short* __restrict__ kv, int M)
{
    __shared__ __align__(16) __bf16 As[64][72];
    __shared__ __align__(16) __bf16 Bs[128][72];
    const int y = blockIdx.y;
    const unsigned short* A = (y < 2) ? x : spat;
    unsigned short*       C = (y < 2) ? q : kv;
    const int Nc = (y < 2) ? 256 : 512;
    const int nB = y * 128;                       // row base in W / bias
    const int nC = (y < 2) ? nB : nB - 256;       // col base in C
    gemm_body(As, Bs, A, W, bias, C, M, Nc, 256, blockIdx.x * 64, nB, nC, 0);
}

// ====== attention: block per node, wave per head; bf16 q/kv/ao ===============
__global__ __launch_bounds__(256) void attn_kernel(
    const unsigned short* __restrict__ q,    // [N, 256]
    const unsigned short* __restrict__ kv,   // [N, 512] (k | v)
    const int* __restrict__ nbr,             // [N, KCAP]
    const int* __restrict__ cnt,             // [N]
    unsigned short* __restrict__ ao)         // [N, 256]
{
    const int n    = blockIdx.x;
    const int tid  = threadIdx.x;
    const int h    = tid >> 6;
    const int lane = tid & 63;

    __shared__ float sc[NHEAD][KCAP];
    __shared__ int   nbs[KCAP];

    int deg = cnt[n];
    if (deg > KCAP) deg = KCAP;
    const bool iso = (deg == 0);
    if (iso) deg = 1;

    if (tid < KCAP)
        nbs[tid] = (tid < deg) ? (iso ? n : nbr[n * KCAP + tid]) : 0;
    __syncthreads();

    // ---- scores: 8 lane-groups of 8 ----
    {
        const int sub = lane & 7;
        const int grp = lane >> 3;
        float qf[8];
        {
            uint4 qu = *(const uint4*)&q[(size_t)n * DIM + h * DHEAD + sub * 8];
            qf[0] = bflo(qu.x); qf[1] = bfhi(qu.x);
            qf[2] = bflo(qu.y); qf[3] = bfhi(qu.y);
            qf[4] = bflo(qu.z); qf[5] = bfhi(qu.z);
            qf[6] = bflo(qu.w); qf[7] = bfhi(qu.w);
        }
        const int nit = (deg + 7) >> 3;
        for (int it = 0; it < nit; ++it) {
            int j  = it * 8 + grp;
            int jc = (j < deg) ? j : (deg - 1);
            int nb = nbs[jc];
            uint4 ku = *(const uint4*)&kv[(size_t)nb * 512 + h * DHEAD + sub * 8];
            float p = qf[0] * bflo(ku.x);
            p = fmaf(qf[1], bfhi(ku.x), p);
            p = fmaf(qf[2], bflo(ku.y), p);
            p = fmaf(qf[3], bfhi(ku.y), p);
            p = fmaf(qf[4], bflo(ku.z), p);
            p = fmaf(qf[5], bfhi(ku.z), p);
            p = fmaf(qf[6], bflo(ku.w), p);
            p = fmaf(qf[7], bfhi(ku.w), p);
            p += __shfl_xor(p, 1, 64);
            p += __shfl_xor(p, 2, 64);
            p += __shfl_xor(p, 4, 64);
            if (sub == 0 && j < deg) sc[h][j] = p * 0.125f;   // 1/sqrt(64)
        }
    }
    __syncthreads();

    // ---- softmax over deg scores (per wave) ----
    {
        float s  = (lane < deg) ? sc[h][lane] : -1e30f;
        float mx = s;
#pragma unroll
        for (int m = 32; m >= 1; m >>= 1) mx = fmaxf(mx, __shfl_xor(mx, m, 64));
        float e   = (lane < deg) ? __expf(s - mx) : 0.0f;
        float sum = e;
#pragma unroll
        for (int m = 32; m >= 1; m >>= 1) sum += __shfl_xor(sum, m, 64);
        float inv = 1.0f / sum;
        if (lane < KCAP) sc[h][lane] = e * inv;
    }
    __syncthreads();

    // ---- PV: 4 lane-quarters of 16; 4 neighbors/iter, 4 dims/lane ----
    {
        const int quarter = lane >> 4;
        const int d0      = (lane & 15) * 4;
        float a0 = 0.f, a1 = 0.f, a2 = 0.f, a3 = 0.f;
        for (int j = 0; j < deg; j += 4) {
            int j0 = j + quarter;
            int jc = (j0 < deg) ? j0 : (deg - 1);
            int nb = nbs[jc];
            uint2 u = *(const uint2*)&kv[(size_t)nb * 512 + 256 + h * DHEAD + d0];
            float w = (j0 < deg) ? sc[h][j0] : 0.f;
            a0 = fmaf(w, bflo(u.x), a0);
            a1 = fmaf(w, bfhi(u.x), a1);
            a2 = fmaf(w, bflo(u.y), a2);
            a3 = fmaf(w, bfhi(u.y), a3);
        }
        a0 += __shfl_xor(a0, 16, 64); a0 += __shfl_xor(a0, 32, 64);
        a1 += __shfl_xor(a1, 16, 64); a1 += __shfl_xor(a1, 32, 64);
        a2 += __shfl_xor(a2, 16, 64); a2 += __shfl_xor(a2, 32, 64);
        a3 += __shfl_xor(a3, 16, 64); a3 += __shfl_xor(a3, 32, 64);
        if (lane < 16) {
            uint2 o;
            o.x = (unsigned)f2bf(a0) | ((unsigned)f2bf(a1) << 16);
            o.y = (unsigned)f2bf(a2) | ((unsigned)f2bf(a3) << 16);
            *(uint2*)&ao[(size_t)n * DIM + h * DHEAD + d0] = o;
        }
    }
}

// ===== fused residual-add + layernorm, wave per row; bf16 I/O, fp32 math =====
__global__ __launch_bounds__(256) void ln_add_kernel(
    const unsigned short* __restrict__ x, const unsigned short* __restrict__ t,
    const float* __restrict__ g, const float* __restrict__ b,
    unsigned short* __restrict__ xout, void* __restrict__ dout,
    int final_out, const int* __restrict__ flag)
{
    const int wave = threadIdx.x >> 6;
    const int lane = threadIdx.x & 63;
    const int row  = blockIdx.x * 4 + wave;   // grid = N/4

    const ushort4 xu = *(const ushort4*)&x[(size_t)row * DIM + lane * 4];
    const ushort4 tu = *(const ushort4*)&t[(size_t)row * DIM + lane * 4];
    float v[4];
    v[0] = bflo(xu.x) + bflo(tu.x);
    v[1] = bflo(xu.y) + bflo(tu.y);
    v[2] = bflo(xu.z) + bflo(tu.z);
    v[3] = bflo(xu.w) + bflo(tu.w);

    float s = 0.f, ss = 0.f;
#pragma unroll
    for (int i = 0; i < 4; ++i) { s += v[i]; ss += v[i] * v[i]; }
#pragma unroll
    for (int m = 32; m >= 1; m >>= 1) {
        s  += __shfl_xor(s, m, 64);
        ss += __shfl_xor(ss, m, 64);
    }
    const float mu  = s * (1.0f / DIM);
    const float var = ss * (1.0f / DIM) - mu * mu;
    const float r   = rsqrtf(var + 1e-5f);

    float o[4];
#pragma unroll
    for (int i = 0; i < 4; ++i) {
        int c = lane * 4 + i;
        o[i] = (v[i] - mu) * r * g[c] + b[c];
    }
    if (final_out) {
        if (flag[0]) {
            *(float4*)&((float*)dout)[(size_t)row * DIM + lane * 4] =
                make_float4(o[0], o[1], o[2], o[3]);
        } else {
            ushort4 u;
            u.x = f2bf(o[0]); u.y = f2bf(o[1]); u.z = f2bf(o[2]); u.w = f2bf(o[3]);
            *(ushort4*)&((unsigned short*)dout)[(size_t)row * DIM + lane * 4] = u;
        }
    } else {
        ushort4 u;
        u.x = f2bf(o[0]); u.y = f2bf(o[1]); u.z = f2bf(o[2]); u.w = f2bf(o[3]);
        *(ushort4*)&xout[(size_t)row * DIM + lane * 4] = u;
    }
}

// =============== launch ======================================================
extern "C" void kernel_launch(void* const* d_in, const int* in_sizes, int n_in,
                              void* d_out, int out_size, void* d_ws, size_t ws_size,
                              hipStream_t stream) {
    const int* ei = (const int*)d_in[14];

    char* ws = (char*)d_ws;
    size_t off = 0;
    auto alloc = [&](size_t bytes) -> void* {
        void* p = ws + off;
        off = (off + bytes + 255) & ~(size_t)255;
        return p;
    };

    // bf16 canon: expr(0), spatial(1), in_proj_w(2), out_proj_w(4), ffn_w1(6), ffn_w2(8)
    const int bidx[6] = { 0, 1, 2, 4, 6, 8 };
    const int bnn[6]  = { N_NODES * DIM, N_NODES * DIM,
                          NLAYER * 3 * DIM * DIM, NLAYER * DIM * DIM,
                          NLAYER * 2 * DIM * DIM, NLAYER * DIM * 2 * DIM };
    ConvBfArgs cb;
    unsigned short* canb[6];
    for (int i = 0; i < 6; ++i) {
        canb[i] = (unsigned short*)alloc((size_t)bnn[i] * 2);
        cb.src[i] = d_in[bidx[i]];
        cb.dst[i] = canb[i];
        cb.n[i]   = bnn[i];
    }
    const unsigned short* expr_b = canb[0];
    const unsigned short* spat_b = canb[1];
    const unsigned short* ipw    = canb[2];
    const unsigned short* opw    = canb[3];
    const unsigned short* w1     = canb[4];
    const unsigned short* w2     = canb[5];

    // fp32 canon: in_proj_b(3), out_proj_b(5), ffn_b1(7), ffn_b2(9), ln params(10..13)
    const int fidx[8] = { 3, 5, 7, 9, 10, 11, 12, 13 };
    const int fn[8]   = { NLAYER * 3 * DIM, NLAYER * DIM, NLAYER * 2 * DIM,
                          NLAYER * DIM, NLAYER * DIM, NLAYER * DIM,
                          NLAYER * DIM, NLAYER * DIM };
    ConvF32Args cf;
    float* canf[8];
    for (int i = 0; i < 8; ++i) {
        canf[i] = (float*)alloc((size_t)fn[i] * 4);
        cf.src[i] = d_in[fidx[i]];
        cf.dst[i] = canf[i];
        cf.n[i]   = fn[i];
    }

    unsigned short* x_buf  = (unsigned short*)alloc((size_t)N_NODES * DIM * 2);
    unsigned short* q_buf  = (unsigned short*)alloc((size_t)N_NODES * DIM * 2);
    unsigned short* kv_buf = (unsigned short*)alloc((size_t)N_NODES * 2 * DIM * 2);
    unsigned short* ao_buf = (unsigned short*)alloc((size_t)N_NODES * DIM * 2);
    unsigned short* h_buf  = (unsigned short*)alloc((size_t)N_NODES * 2 * DIM * 2);
    unsigned short* t_buf  = (unsigned short*)alloc((size_t)N_NODES * DIM * 2);
    int* cnt  = (int*)alloc((size_t)N_NODES * 4);
    int* nbr  = (int*)alloc((size_t)N_NODES * KCAP * 4);
    int* flag = (int*)alloc(256);

    sniff_kernel<<<1, 256, 0, stream>>>((const unsigned short*)d_in[0], flag);
    conv_bf16_kernel<<<dim3((N_NODES * DIM) / 1024, 6), 256, 0, stream>>>(cb, flag);
    conv_f32_kernel<<<dim3(2, 8), 256, 0, stream>>>(cf, flag);
    zero_cnt_kernel<<<(N_NODES + 255) / 256, 256, 0, stream>>>(cnt);
    build_nbr_kernel<<<(NEDGE + 255) / 256, 256, 0, stream>>>(ei, cnt, nbr);

    for (int i = 0; i < NLAYER; ++i) {
        const unsigned short* Wqkv = ipw + (size_t)i * 3 * DIM * DIM;
        const float*          bqkv = canf[0] + (size_t)i * 3 * DIM;
        const unsigned short* xin  = (i == 0) ? expr_b : x_buf;

        // q | kv fused projection
        qkv_kernel<<<dim3(NBM64, 6), 256, 0, stream>>>(
            xin, spat_b, Wqkv, bqkv, q_buf, kv_buf, N_NODES);
        // attention
        attn_kernel<<<N_NODES, 256, 0, stream>>>(q_buf, kv_buf, nbr, cnt, ao_buf);
        // t = ao @ Wo^T + bo
        gemm_kernel<<<dim3(NBM64, 2), 256, 0, stream>>>(
            ao_buf, opw + (size_t)i * DIM * DIM, canf[1] + (size_t)i * DIM,
            t_buf, N_NODES, DIM, DIM, 0);
        // x = LN(xin + t)
        ln_add_kernel<<<N_NODES / 4, 256, 0, stream>>>(
            xin, t_buf, canf[4] + (size_t)i * DIM, canf[5] + (size_t)i * DIM,
            x_buf, nullptr, 0, flag);
        // h = gelu(x @ W1^T + b1)
        gemm_kernel<<<dim3(NBM64, 4), 256, 0, stream>>>(
            x_buf, w1 + (size_t)i * 2 * DIM * DIM, canf[2] + (size_t)i * 2 * DIM,
            h_buf, N_NODES, 2 * DIM, DIM, 1);
        // t = h @ W2^T + b2
        gemm_kernel<<<dim3(NBM64, 2), 256, 0, stream>>>(
            h_buf, w2 + (size_t)i * DIM * 2 * DIM, canf[3] + (size_t)i * DIM,
            t_buf, N_NODES, DIM, 2 * DIM, 0);
        // x = LN(x + t); final layer writes d_out (flag-gated dtype)
        ln_add_kernel<<<N_NODES / 4, 256, 0, stream>>>(
            x_buf, t_buf, canf[6] + (size_t)i * DIM, canf[7] + (size_t)i * DIM,
            x_buf, d_out, (i == NLAYER - 1) ? 1 : 0, flag);
    }
}

// Round 10
// 440.243 us; speedup vs baseline: 2.8151x; 1.0208x over previous
//
#include <hip/hip_runtime.h>

#define N_NODES 20000
#define DIM 256
#define NHEAD 4
#define DHEAD 64
#define NLAYER 2
#define NEDGE 320000
#define KCAP 48
#define NBM64 313   // ceil(20000/64)

typedef __bf16 v8bf __attribute__((ext_vector_type(8)));
typedef __bf16 v2bf __attribute__((ext_vector_type(2)));
typedef float v4f __attribute__((ext_vector_type(4)));

union LU  { uint4 u; v8bf v; };
union U32 { unsigned u; v2bf v; };

__device__ __forceinline__ unsigned short f2bf(float f) {
    unsigned u = __float_as_uint(f);
    unsigned r = u + 0x7FFFu + ((u >> 16) & 1u);   // RNE
    return (unsigned short)(r >> 16);
}
__device__ __forceinline__ float bflo(unsigned u) { return __uint_as_float(u << 16); }
__device__ __forceinline__ float bfhi(unsigned u) { return __uint_as_float(u & 0xFFFF0000u); }

// =============== sniffer + cnt zero fused ====================================
__global__ void sniffzero_kernel(const unsigned short* __restrict__ p,
                                 int* __restrict__ flag, int* __restrict__ cnt) {
    if (blockIdx.x == 0) {
        __shared__ int s;
        if (threadIdx.x == 0) s = 0;
        __syncthreads();
        int c = 0;
        for (int i = threadIdx.x; i < 4096; i += 256) {
            unsigned short u = p[i];
            unsigned e = (u >> 7) & 0xFFu;
            if (e == 0xFFu) c++;
            else if (e == 0u && (u & 0x7Fu)) c++;
        }
        atomicAdd(&s, c);
        __syncthreads();
        if (threadIdx.x == 0) flag[0] = (s >= 4) ? 1 : 0;
    } else {
        int i = (blockIdx.x - 1) * 256 + threadIdx.x;
        if (i < N_NODES) cnt[i] = 0;
    }
}

// ===== conv to bf16 canon: 6 tensors (embeds + weights) ======================
struct ConvBfArgs { const void* src[6]; unsigned short* dst[6]; int n[6]; };

__global__ void conv_bf16_kernel(ConvBfArgs a, const int* __restrict__ flag) {
    const int t  = blockIdx.y;
    const int n  = a.n[t];
    const int i0 = (blockIdx.x * 256 + threadIdx.x) * 4;
    if (i0 >= n) return;
    unsigned short* dst = a.dst[t];
    if (flag[0]) {
        float4 v = *(const float4*)((const float*)a.src[t] + i0);
        ushort4 o;
        o.x = f2bf(v.x); o.y = f2bf(v.y); o.z = f2bf(v.z); o.w = f2bf(v.w);
        *(ushort4*)(dst + i0) = o;
    } else {
        ushort4 u = *(const ushort4*)((const unsigned short*)a.src[t] + i0);
        *(ushort4*)(dst + i0) = u;
    }
}

// ===== conv to fp32 canon: biases + LN params (8 small tensors) ==============
struct ConvF32Args { const void* src[8]; float* dst[8]; int n[8]; };

__global__ void conv_f32_kernel(ConvF32Args a, const int* __restrict__ flag) {
    const int t  = blockIdx.y;
    const int n  = a.n[t];
    const int i0 = (blockIdx.x * 256 + threadIdx.x) * 4;
    if (i0 >= n) return;
    float* dst = a.dst[t];
    if (flag[0]) {
        float4 v = *(const float4*)((const float*)a.src[t] + i0);
        *(float4*)(dst + i0) = v;
    } else {
        ushort4 u = *(const ushort4*)((const unsigned short*)a.src[t] + i0);
        *(float4*)(dst + i0) = make_float4(bflo(u.x), bflo(u.y), bflo(u.z), bflo(u.w));
    }
}

__global__ void build_nbr_kernel(const int* __restrict__ ei,
                                 int* __restrict__ cnt, int* __restrict__ nbr) {
    int e = blockIdx.x * 256 + threadIdx.x;
    if (e >= NEDGE) return;
    int s = ei[e];
    int t = ei[NEDGE + e];
    int slot = atomicAdd(&cnt[t], 1);
    if (slot < KCAP) nbr[t * KCAP + slot] = s;
}

// ==== MFMA GEMM body: 64x128 tile, register-prefetch K-loop (r9-proven) ======
__device__ __forceinline__ void gemm_body(
    __bf16 (*As)[72], __bf16 (*Bs)[72],
    const unsigned short* __restrict__ A, const unsigned short* __restrict__ B,
    const float* __restrict__ bias, unsigned short* __restrict__ C,
    int M, int Nc, int Kd, int m0, int nB, int nC, int do_gelu)
{
    const int tid  = threadIdx.x;
    const int wave = tid >> 6;
    const int lane = tid & 63;
    const int wn0  = wave * 32;
    const int lm   = lane & 15;
    const int lk   = (lane >> 4) * 8;
    const int srow = tid >> 3;
    const int scol = (tid & 7) << 3;

    uint4 pa[2], pb[4];
#pragma unroll
    for (int i = 0; i < 2; ++i) {
        int row = srow + i * 32;
        pa[i] = make_uint4(0u, 0u, 0u, 0u);
        if (m0 + row < M)
            pa[i] = *(const uint4*)&A[(size_t)(m0 + row) * Kd + scol];
    }
#pragma unroll
    for (int i = 0; i < 4; ++i) {
        int row = srow + i * 32;
        pb[i] = *(const uint4*)&B[(size_t)(nB + row) * Kd + scol];
    }

    v4f acc[4][2] = {};

    for (int k0 = 0; k0 < Kd; k0 += 64) {
#pragma unroll
        for (int i = 0; i < 2; ++i) { LU t; t.u = pa[i]; *(v8bf*)&As[srow + i * 32][scol] = t.v; }
#pragma unroll
        for (int i = 0; i < 4; ++i) { LU t; t.u = pb[i]; *(v8bf*)&Bs[srow + i * 32][scol] = t.v; }
        __syncthreads();

        const int kn = k0 + 64;
        if (kn < Kd) {
#pragma unroll
            for (int i = 0; i < 2; ++i) {
                int row = srow + i * 32;
                pa[i] = make_uint4(0u, 0u, 0u, 0u);
                if (m0 + row < M)
                    pa[i] = *(const uint4*)&A[(size_t)(m0 + row) * Kd + kn + scol];
            }
#pragma unroll
            for (int i = 0; i < 4; ++i) {
                int row = srow + i * 32;
                pb[i] = *(const uint4*)&B[(size_t)(nB + row) * Kd + kn + scol];
            }
        }

#pragma unroll
        for (int ks = 0; ks < 2; ++ks) {
            v8bf af[4], bq[2];
#pragma unroll
            for (int mi = 0; mi < 4; ++mi)
                af[mi] = *(const v8bf*)&As[mi * 16 + lm][ks * 32 + lk];
#pragma unroll
            for (int ni = 0; ni < 2; ++ni)
                bq[ni] = *(const v8bf*)&Bs[wn0 + ni * 16 + lm][ks * 32 + lk];
#pragma unroll
            for (int mi = 0; mi < 4; ++mi)
#pragma unroll
                for (int ni = 0; ni < 2; ++ni)
                    acc[mi][ni] = __builtin_amdgcn_mfma_f32_16x16x32_bf16(
                        af[mi], bq[ni], acc[mi][ni], 0, 0, 0);
        }
        __syncthreads();
    }

    const int rq = (lane >> 4) << 2;
#pragma unroll
    for (int ni = 0; ni < 2; ++ni) {
        int colb = wn0 + ni * 16 + lm;
        float bv = bias[nB + colb];
        int colc = nC + colb;
#pragma unroll
        for (int mi = 0; mi < 4; ++mi) {
#pragma unroll
            for (int r = 0; r < 4; ++r) {
                int row = m0 + mi * 16 + rq + r;
                if (row >= M) continue;
                float v = acc[mi][ni][r] + bv;
                if (do_gelu) v = 0.5f * v * (1.0f + erff(v * 0.7071067811865475f));
                C[(size_t)row * Nc + colc] = f2bf(v);
            }
        }
    }
}

// Generic GEMM (used for ffn1): grid (ceil(M/64), Nc/128)
__global__ __launch_bounds__(256) void gemm_kernel(
    const unsigned short* __restrict__ A, const unsigned short* __restrict__ B,
    const float* __restrict__ bias, unsigned short* __restrict__ C,
    int M, int Nc, int Kd, int do_gelu)
{
    __shared__ __align__(16) __bf16 As[64][72];
    __shared__ __align__(16) __bf16 Bs[128][72];
    const int n0 = blockIdx.y * 128;
    gemm_body(As, Bs, A, B, bias, C, M, Nc, Kd, blockIdx.x * 64, n0, n0, do_gelu);
}

// Fused q+kv projection: grid (ceil(M/64), 6)
__global__ __launch_bounds__(256) void qkv_kernel(
    const unsigned short* __restrict__ x, const unsigned short* __restrict__ spat,
    const unsigned short* __restrict__ W, const float* __restrict__ bias,
    unsigned short* __restrict__ q, unsigned short* __restrict__ kv, int M)
{
    __shared__ __align__(16) __bf16 As[64][72];
    __shared__ __align__(16) __bf16 Bs[128][72];
    const int y = blockIdx.y;
    const unsigned short* A = (y < 2) ? x : spat;
    unsigned short*       C = (y < 2) ? q : kv;
    const int Nc = (y < 2) ? 256 : 512;
    const int nB = y * 128;
    const int nC = (y < 2) ? nB : nB - 256;
    gemm_body(As, Bs, A, W, bias, C, M, Nc, 256, blockIdx.x * 64, nB, nC, 0);
}

// ==== Fused GEMM + residual + LayerNorm: tile 64 x 256 (full row in block) ===
// out = LN(xres + A@B^T + bias); final_out: write d_out (dtype per flag).
__global__ __launch_bounds__(256) void gemm_ln_kernel(
    const unsigned short* __restrict__ A, const unsigned short* __restrict__ B,
    const float* __restrict__ bias, const unsigned short* __restrict__ xres,
    const float* __restrict__ g, const float* __restrict__ bb,
    unsigned short* __restrict__ xout, void* __restrict__ dout,
    int M, int Kd, int final_out, const int* __restrict__ flag)
{
    __shared__ __align__(16) __bf16 As[64][72];
    __shared__ __align__(16) __bf16 Bs[256][72];
    __shared__ float partS[4][64], partSS[4][64];
    __shared__ float totMu[64], totR[64];

    const int tid  = threadIdx.x;
    const int m0   = blockIdx.x * 64;
    const int wave = tid >> 6;
    const int lane = tid & 63;
    const int wn0  = wave * 64;
    const int lm   = lane & 15;
    const int lk   = (lane >> 4) * 8;
    const int srow = tid >> 3;
    const int scol = (tid & 7) << 3;

    uint4 pa[2], pb[8];
#pragma unroll
    for (int i = 0; i < 2; ++i) {
        int row = srow + i * 32;
        pa[i] = make_uint4(0u, 0u, 0u, 0u);
        if (m0 + row < M)
            pa[i] = *(const uint4*)&A[(size_t)(m0 + row) * Kd + scol];
    }
#pragma unroll
    for (int i = 0; i < 8; ++i) {
        int row = srow + i * 32;
        pb[i] = *(const uint4*)&B[(size_t)row * Kd + scol];
    }

    v4f acc[4][4] = {};

    for (int k0 = 0; k0 < Kd; k0 += 64) {
#pragma unroll
        for (int i = 0; i < 2; ++i) { LU t; t.u = pa[i]; *(v8bf*)&As[srow + i * 32][scol] = t.v; }
#pragma unroll
        for (int i = 0; i < 8; ++i) { LU t; t.u = pb[i]; *(v8bf*)&Bs[srow + i * 32][scol] = t.v; }
        __syncthreads();

        const int kn = k0 + 64;
        if (kn < Kd) {
#pragma unroll
            for (int i = 0; i < 2; ++i) {
                int row = srow + i * 32;
                pa[i] = make_uint4(0u, 0u, 0u, 0u);
                if (m0 + row < M)
                    pa[i] = *(const uint4*)&A[(size_t)(m0 + row) * Kd + kn + scol];
            }
#pragma unroll
            for (int i = 0; i < 8; ++i) {
                int row = srow + i * 32;
                pb[i] = *(const uint4*)&B[(size_t)row * Kd + kn + scol];
            }
        }

#pragma unroll
        for (int ks = 0; ks < 2; ++ks) {
            v8bf af[4], bq[4];
#pragma unroll
            for (int mi = 0; mi < 4; ++mi)
                af[mi] = *(const v8bf*)&As[mi * 16 + lm][ks * 32 + lk];
#pragma unroll
            for (int ni = 0; ni < 4; ++ni)
                bq[ni] = *(const v8bf*)&Bs[wn0 + ni * 16 + lm][ks * 32 + lk];
#pragma unroll
            for (int mi = 0; mi < 4; ++mi)
#pragma unroll
                for (int ni = 0; ni < 4; ++ni)
                    acc[mi][ni] = __builtin_amdgcn_mfma_f32_16x16x32_bf16(
                        af[mi], bq[ni], acc[mi][ni], 0, 0, 0);
        }
        __syncthreads();
    }

    // --- epilogue: v = acc + bias + residual; per-row LN over all 256 cols ---
    const int rq = (lane >> 4) << 2;
    float gv[4], bv2[4], biasv[4];
#pragma unroll
    for (int ni = 0; ni < 4; ++ni) {
        int col = wn0 + ni * 16 + lm;
        biasv[ni] = bias[col];
        gv[ni]    = g[col];
        bv2[ni]   = bb[col];
    }

    float sl[4][4] = {}, ssl[4][4] = {};
#pragma unroll
    for (int mi = 0; mi < 4; ++mi) {
#pragma unroll
        for (int r = 0; r < 4; ++r) {
            int row = m0 + mi * 16 + rq + r;
#pragma unroll
            for (int ni = 0; ni < 4; ++ni) {
                int col = wn0 + ni * 16 + lm;
                float resv = bflo((unsigned)xres[(size_t)row * DIM + col]);
                float v = acc[mi][ni][r] + biasv[ni] + resv;
                acc[mi][ni][r] = v;
                sl[mi][r]  += v;
                ssl[mi][r] += v * v;
            }
        }
    }
    // reduce across the 16 lanes of each quarter
#pragma unroll
    for (int mi = 0; mi < 4; ++mi)
#pragma unroll
        for (int r = 0; r < 4; ++r) {
#pragma unroll
            for (int m = 1; m <= 8; m <<= 1) {
                sl[mi][r]  += __shfl_xor(sl[mi][r],  m, 64);
                ssl[mi][r] += __shfl_xor(ssl[mi][r], m, 64);
            }
        }
    if (lm == 0) {
#pragma unroll
        for (int mi = 0; mi < 4; ++mi)
#pragma unroll
            for (int r = 0; r < 4; ++r) {
                partS[wave][mi * 16 + rq + r]  = sl[mi][r];
                partSS[wave][mi * 16 + rq + r] = ssl[mi][r];
            }
    }
    __syncthreads();
    if (tid < 64) {
        float S = partS[0][tid] + partS[1][tid] + partS[2][tid] + partS[3][tid];
        float SS = partSS[0][tid] + partSS[1][tid] + partSS[2][tid] + partSS[3][tid];
        float mu  = S * (1.0f / DIM);
        float var = SS * (1.0f / DIM) - mu * mu;
        totMu[tid] = mu;
        totR[tid]  = rsqrtf(var + 1e-5f);
    }
    __syncthreads();

#pragma unroll
    for (int mi = 0; mi < 4; ++mi) {
#pragma unroll
        for (int r = 0; r < 4; ++r) {
            int lrow = mi * 16 + rq + r;
            int row  = m0 + lrow;
            if (row >= M) continue;
            float mu = totMu[lrow];
            float rv = totR[lrow];
#pragma unroll
            for (int ni = 0; ni < 4; ++ni) {
                int col = wn0 + ni * 16 + lm;
                float o = (acc[mi][ni][r] - mu) * rv * gv[ni] + bv2[ni];
                if (final_out) {
                    if (flag[0]) ((float*)dout)[(size_t)row * DIM + col] = o;
                    else ((unsigned short*)dout)[(size_t)row * DIM + col] = f2bf(o);
                } else {
                    xout[(size_t)row * DIM + col] = f2bf(o);
                }
            }
        }
    }
}

// ====== attention: block per node, wave per head; barrier-free ===============
__global__ __launch_bounds__(256) void attn_kernel(
    const unsigned short* __restrict__ q,    // [N, 256]
    const unsigned short* __restrict__ kv,   // [N, 512] (k | v)
    const int* __restrict__ nbr,             // [N, KCAP]
    const int* __restrict__ cnt,             // [N]
    unsigned short* __restrict__ ao)         // [N, 256]
{
    const int n    = blockIdx.x;
    const int tid  = threadIdx.x;
    const int h    = tid >> 6;
    const int lane = tid & 63;

    __shared__ float sc[NHEAD][KCAP];
    __shared__ int   nbs[NHEAD][KCAP];

    int deg = cnt[n];
    if (deg > KCAP) deg = KCAP;
    const bool iso = (deg == 0);
    if (iso) deg = 1;

    // per-wave neighbor list (no cross-wave sharing -> no barriers anywhere)
    if (lane < KCAP)
        nbs[h][lane] = (lane < deg) ? (iso ? n : nbr[n * KCAP + lane]) : 0;

    // ---- scores: 8 lane-groups of 8 ----
    {
        const int sub = lane & 7;
        const int grp = lane >> 3;
        const uint4 qu = *(const uint4*)&q[(size_t)n * DIM + h * DHEAD + sub * 8];
        const unsigned short* kbase = kv + h * DHEAD + sub * 8;
        const int nit = (deg + 7) >> 3;
        for (int it = 0; it < nit; ++it) {
            int j  = it * 8 + grp;
            int nb = nbs[h][j];
            uint4 ku = *(const uint4*)&kbase[(size_t)nb * 512];
#if __has_builtin(__builtin_amdgcn_fdot2_f32_bf16)
            U32 a0{qu.x}, a1{qu.y}, a2{qu.z}, a3{qu.w};
            U32 b0{ku.x}, b1{ku.y}, b2{ku.z}, b3{ku.w};
            float p = __builtin_amdgcn_fdot2_f32_bf16(a0.v, b0.v, 0.0f, false);
            p = __builtin_amdgcn_fdot2_f32_bf16(a1.v, b1.v, p, false);
            p = __builtin_amdgcn_fdot2_f32_bf16(a2.v, b2.v, p, false);
            p = __builtin_amdgcn_fdot2_f32_bf16(a3.v, b3.v, p, false);
#else
            float p = bflo(qu.x) * bflo(ku.x);
            p = fmaf(bfhi(qu.x), bfhi(ku.x), p);
            p = fmaf(bflo(qu.y), bflo(ku.y), p);
            p = fmaf(bfhi(qu.y), bfhi(ku.y), p);
            p = fmaf(bflo(qu.z), bflo(ku.z), p);
            p = fmaf(bfhi(qu.z), bfhi(ku.z), p);
            p = fmaf(bflo(qu.w), bflo(ku.w), p);
            p = fmaf(bfhi(qu.w), bfhi(ku.w), p);
#endif
            p += __shfl_xor(p, 1, 64);
            p += __shfl_xor(p, 2, 64);
            p += __shfl_xor(p, 4, 64);
            if (sub == 0 && j < deg) sc[h][j] = p * 0.125f;   // 1/sqrt(64)
        }
    }

    // ---- softmax (per wave; sc is wave-private) ----
    {
        float s  = (lane < deg) ? sc[h][lane] : -1e30f;
        float mx = s;
#pragma unroll
        for (int m = 32; m >= 1; m >>= 1) mx = fmaxf(mx, __shfl_xor(mx, m, 64));
        float e   = (lane < deg) ? __expf(s - mx) : 0.0f;
        float sum = e;
#pragma unroll
        for (int m = 32; m >= 1; m >>= 1) sum += __shfl_xor(sum, m, 64);
        float inv = 1.0f / sum;
        if (lane < KCAP) sc[h][lane] = e * inv;   // zero for lane >= deg
    }

    // ---- PV: 4 lane-quarters of 16; clamp-free (sc/nbs zero-padded) ----
    {
        const int quarter = lane >> 4;
        const int d0      = (lane & 15) * 4;
        const unsigned short* vbase = kv + 256 + h * DHEAD + d0;
        const int dmax = (deg + 3) & ~3;
        float a0 = 0.f, a1 = 0.f, a2 = 0.f, a3 = 0.f;
        for (int j = 0; j < dmax; j += 4) {
            int j0 = j + quarter;
            int nb = nbs[h][j0];
            uint2 u = *(const uint2*)&vbase[(size_t)nb * 512];
            float w = sc[h][j0];
            a0 = fmaf(w, bflo(u.x), a0);
            a1 = fmaf(w, bfhi(u.x), a1);
            a2 = fmaf(w, bflo(u.y), a2);
            a3 = fmaf(w, bfhi(u.y), a3);
        }
        a0 += __shfl_xor(a0, 16, 64); a0 += __shfl_xor(a0, 32, 64);
        a1 += __shfl_xor(a1, 16, 64); a1 += __shfl_xor(a1, 32, 64);
        a2 += __shfl_xor(a2, 16, 64); a2 += __shfl_xor(a2, 32, 64);
        a3 += __shfl_xor(a3, 16, 64); a3 += __shfl_xor(a3, 32, 64);
        if (lane < 16) {
            uint2 o;
            o.x = (unsigned)f2bf(a0) | ((unsigned)f2bf(a1) << 16);
            o.y = (unsigned)f2bf(a2) | ((unsigned)f2bf(a3) << 16);
            *(uint2*)&ao[(size_t)n * DIM + h * DHEAD + d0] = o;
        }
    }
}

// =============== launch ======================================================
extern "C" void kernel_launch(void* const* d_in, const int* in_sizes, int n_in,
                              void* d_out, int out_size, void* d_ws, size_t ws_size,
                              hipStream_t stream) {
    const int* ei = (const int*)d_in[14];

    char* ws = (char*)d_ws;
    size_t off = 0;
    auto alloc = [&](size_t bytes) -> void* {
        void* p = ws + off;
        off = (off + bytes + 255) & ~(size_t)255;
        return p;
    };

    const int bidx[6] = { 0, 1, 2, 4, 6, 8 };
    const int bnn[6]  = { N_NODES * DIM, N_NODES * DIM,
                          NLAYER * 3 * DIM * DIM, NLAYER * DIM * DIM,
                          NLAYER * 2 * DIM * DIM, NLAYER * DIM * 2 * DIM };
    ConvBfArgs cb;
    unsigned short* canb[6];
    for (int i = 0; i < 6; ++i) {
        canb[i] = (unsigned short*)alloc((size_t)bnn[i] * 2);
        cb.src[i] = d_in[bidx[i]];
        cb.dst[i] = canb[i];
        cb.n[i]   = bnn[i];
    }
    const unsigned short* expr_b = canb[0];
    const unsigned short* spat_b = canb[1];
    const unsigned short* ipw    = canb[2];
    const unsigned short* opw    = canb[3];
    const unsigned short* w1     = canb[4];
    const unsigned short* w2     = canb[5];

    const int fidx[8] = { 3, 5, 7, 9, 10, 11, 12, 13 };
    const int fn[8]   = { NLAYER * 3 * DIM, NLAYER * DIM, NLAYER * 2 * DIM,
                          NLAYER * DIM, NLAYER * DIM, NLAYER * DIM,
                          NLAYER * DIM, NLAYER * DIM };
    ConvF32Args cf;
    float* canf[8];
    for (int i = 0; i < 8; ++i) {
        canf[i] = (float*)alloc((size_t)fn[i] * 4);
        cf.src[i] = d_in[fidx[i]];
        cf.dst[i] = canf[i];
        cf.n[i]   = fn[i];
    }

    unsigned short* x_buf  = (unsigned short*)alloc((size_t)N_NODES * DIM * 2);
    unsigned short* q_buf  = (unsigned short*)alloc((size_t)N_NODES * DIM * 2);
    unsigned short* kv_buf = (unsigned short*)alloc((size_t)N_NODES * 2 * DIM * 2);
    unsigned short* ao_buf = (unsigned short*)alloc((size_t)N_NODES * DIM * 2);
    unsigned short* h_buf  = (unsigned short*)alloc((size_t)N_NODES * 2 * DIM * 2);
    int* cnt  = (int*)alloc((size_t)N_NODES * 4);
    int* nbr  = (int*)alloc((size_t)N_NODES * KCAP * 4);
    int* flag = (int*)alloc(256);

    sniffzero_kernel<<<1 + (N_NODES + 255) / 256, 256, 0, stream>>>(
        (const unsigned short*)d_in[0], flag, cnt);
    conv_bf16_kernel<<<dim3((N_NODES * DIM) / 1024, 6), 256, 0, stream>>>(cb, flag);
    conv_f32_kernel<<<dim3(2, 8), 256, 0, stream>>>(cf, flag);
    build_nbr_kernel<<<(NEDGE + 255) / 256, 256, 0, stream>>>(ei, cnt, nbr);

    for (int i = 0; i < NLAYER; ++i) {
        const unsigned short* Wqkv = ipw + (size_t)i * 3 * DIM * DIM;
        const float*          bqkv = canf[0] + (size_t)i * 3 * DIM;
        const unsigned short* xin  = (i == 0) ? expr_b : x_buf;

        // q | kv fused projection
        qkv_kernel<<<dim3(NBM64, 6), 256, 0, stream>>>(
            xin, spat_b, Wqkv, bqkv, q_buf, kv_buf, N_NODES);
        // attention
        attn_kernel<<<N_NODES, 256, 0, stream>>>(q_buf, kv_buf, nbr, cnt, ao_buf);
        // x = LN(xin + ao @ Wo^T + bo)
        gemm_ln_kernel<<<NBM64, 256, 0, stream>>>(
            ao_buf, opw + (size_t)i * DIM * DIM, canf[1] + (size_t)i * DIM,
            xin, canf[4] + (size_t)i * DIM, canf[5] + (size_t)i * DIM,
            x_buf, nullptr, N_NODES, DIM, 0, flag);
        // h = gelu(x @ W1^T + b1)
        gemm_kernel<<<dim3(NBM64, 4), 256, 0, stream>>>(
            x_buf, w1 + (size_t)i * 2 * DIM * DIM, canf[2] + (size_t)i * 2 * DIM,
            h_buf, N_NODES, 2 * DIM, DIM, 1);
        // x = LN(x + h @ W2^T + b2); final layer -> d_out (dtype per flag)
        gemm_ln_kernel<<<NBM64, 256, 0, stream>>>(
            h_buf, w2 + (size_t)i * DIM * 2 * DIM, canf[3] + (size_t)i * DIM,
            x_buf, canf[6] + (size_t)i * DIM, canf[7] + (size_t)i * DIM,
            x_buf, d_out, N_NODES, 2 * DIM, (i == NLAYER - 1) ? 1 : 0, flag);
    }
}